// Round 2
// baseline (824.811 us; speedup 1.0000x reference)
//
#include <hip/hip_runtime.h>
#include <math.h>

// Problem constants
#define BB   2
#define SS   1024
#define HH   4096
#define NHH  32
#define NKVV 8
#define HDD  128
#define MR   2048   // B*S
#define KVD  1024   // NKV*HD
#define NQKVD 6144  // H + 2*KVD
#define KD   4096
#define KHALF 2048
#define SCALE_F 0.08838834764831845f  // 1/sqrt(128)

typedef __attribute__((ext_vector_type(8))) short bf16x8;
typedef __attribute__((ext_vector_type(4))) float f32x4;

#define MFMA(a, b, c) __builtin_amdgcn_mfma_f32_16x16x32_bf16((a), (b), (c), 0, 0, 0)

__device__ __forceinline__ unsigned short f2bf(float f) {
  union { float f; unsigned u; } v; v.f = f;
  return (unsigned short)((v.u + 0x7fffu + ((v.u >> 16) & 1u)) >> 16);
}

__device__ __forceinline__ void gload_lds16(const void* g, void* l) {
  __builtin_amdgcn_global_load_lds(
      (const __attribute__((address_space(1))) void*)g,
      (__attribute__((address_space(3))) void*)l, 16, 0, 0);
}

// ---------------- conversions ----------------
__global__ void cvt_f32_bf16(const float* __restrict__ in, unsigned short* __restrict__ out, int n4) {
  int i = blockIdx.x * blockDim.x + threadIdx.x;
  if (i >= n4) return;
  float4 v = ((const float4*)in)[i];
  union { unsigned short s[4]; uint2 d; } o;
  o.s[0] = f2bf(v.x); o.s[1] = f2bf(v.y); o.s[2] = f2bf(v.z); o.s[3] = f2bf(v.w);
  ((uint2*)out)[i] = o.d;
}

__global__ void cvt_i32_bf16(const int* __restrict__ in, unsigned short* __restrict__ out, int n4) {
  int i = blockIdx.x * blockDim.x + threadIdx.x;
  if (i >= n4) return;
  int4 v = ((const int4*)in)[i];
  union { unsigned short s[4]; uint2 d; } o;
  o.s[0] = f2bf((float)v.x); o.s[1] = f2bf((float)v.y);
  o.s[2] = f2bf((float)v.z); o.s[3] = f2bf((float)v.w);
  ((uint2*)out)[i] = o.d;
}

// ---------------- split-K GEMM: P += A[M,K] * W[N,K]^T, 128x128 tile, BK=32, KSPLIT=2 ----------------
// blockIdx.z = kz selects K half. fp32 atomicAdd epilogue into zeroed partial buffer
// (exactly 2 commutative adds per address -> deterministic).
__global__ __launch_bounds__(256) void gemm_splitk(
    const unsigned short* __restrict__ A, const unsigned short* __restrict__ W,
    float* __restrict__ P, int N) {
  __shared__ unsigned short ldsA[128 * 32];
  __shared__ unsigned short ldsB[128 * 32];
  const int t = threadIdx.x;
  const int lane = t & 63;
  const int w = t >> 6;
  const int wr = w & 1, wc = w >> 1;
  const int l15 = lane & 15, quad = lane >> 4;
  const int bm = blockIdx.y, bn = blockIdx.x, kz = blockIdx.z;

  const int srow = t >> 2;
  const int scol = (t & 3) * 8;
  const unsigned short* gA = A + (size_t)(bm * 128 + srow) * KD + scol + kz * KHALF;
  const unsigned short* gW = W + (size_t)(bn * 128 + srow) * KD + scol + kz * KHALF;
  unsigned short* lA = ldsA + t * 8;  // wave base + lane*16 bytes (global_load_lds layout rule)
  unsigned short* lB = ldsB + t * 8;

  f32x4 acc[4][4] = {};

  for (int k0 = 0; k0 < KHALF; k0 += 32) {
    __syncthreads();
    gload_lds16(gA + k0, lA);
    gload_lds16(gA + (size_t)64 * KD + k0, lA + 2048);
    gload_lds16(gW + k0, lB);
    gload_lds16(gW + (size_t)64 * KD + k0, lB + 2048);
    __syncthreads();
    bf16x8 af[4], bfr[4];
#pragma unroll
    for (int mi = 0; mi < 4; ++mi)
      af[mi] = *(const bf16x8*)(ldsA + (wr * 64 + mi * 16 + l15) * 32 + quad * 8);
#pragma unroll
    for (int ni = 0; ni < 4; ++ni)
      bfr[ni] = *(const bf16x8*)(ldsB + (wc * 64 + ni * 16 + l15) * 32 + quad * 8);
#pragma unroll
    for (int mi = 0; mi < 4; ++mi)
#pragma unroll
      for (int ni = 0; ni < 4; ++ni)
        acc[mi][ni] = MFMA(af[mi], bfr[ni], acc[mi][ni]);
  }

  // C/D layout: row = quad*4 + r, col = lane&15 (m89-verified)
  const int row0 = bm * 128 + wr * 64 + quad * 4;
  const int col0 = bn * 128 + wc * 64 + l15;
#pragma unroll
  for (int mi = 0; mi < 4; ++mi)
#pragma unroll
    for (int ni = 0; ni < 4; ++ni)
#pragma unroll
      for (int r = 0; r < 4; ++r)
        atomicAdd(P + (size_t)(row0 + mi * 16 + r) * N + col0 + ni * 16, acc[mi][ni][r]);
}

// ---------------- epilogues ----------------
// Q/K columns: scale+bias, bf16, coalesced. grid(5, 2048), block 256, 4 cols/thread.
__global__ void epi_qk(const float* __restrict__ P,
                       const float* __restrict__ sQ, const float* __restrict__ bQ,
                       const float* __restrict__ sK, const float* __restrict__ bK,
                       unsigned short* __restrict__ oQ, unsigned short* __restrict__ oK) {
  const int col = (blockIdx.x * 256 + threadIdx.x) * 4;
  const int row = blockIdx.y;
  float4 v = *(const float4*)(P + (size_t)row * NQKVD + col);
  union { unsigned short s[4]; uint2 d; } o;
  if (col < HH) {
    const float4 s = *(const float4*)(sQ + col);
    const float4 b = *(const float4*)(bQ + col);
    o.s[0] = f2bf(v.x * s.x + b.x); o.s[1] = f2bf(v.y * s.y + b.y);
    o.s[2] = f2bf(v.z * s.z + b.z); o.s[3] = f2bf(v.w * s.w + b.w);
    *(uint2*)(oQ + (size_t)row * HH + col) = o.d;
  } else {
    const int c = col - HH;
    const float4 s = *(const float4*)(sK + c);
    const float4 b = *(const float4*)(bK + c);
    o.s[0] = f2bf(v.x * s.x + b.x); o.s[1] = f2bf(v.y * s.y + b.y);
    o.s[2] = f2bf(v.z * s.z + b.z); o.s[3] = f2bf(v.w * s.w + b.w);
    *(uint2*)(oK + (size_t)row * KVD + c) = o.d;
  }
}

// V columns: scale, bf16, TRANSPOSED store via LDS (64x64 tile). grid(16, 32), block 256.
__global__ void epi_v(const float* __restrict__ P, const float* __restrict__ sV,
                      unsigned short* __restrict__ oVt) {
  __shared__ unsigned short lds_t[64][65];
  const int t = threadIdx.x;
  const int c0 = blockIdx.x * 64;  // V channel tile
  const int r0 = blockIdx.y * 64;  // row tile
  const int c4 = (t & 15) * 4;
  const float4 s = *(const float4*)(sV + c0 + c4);
#pragma unroll
  for (int rr = 0; rr < 4; ++rr) {
    const int rl = (t >> 4) * 4 + rr;
    float4 v = *(const float4*)(P + (size_t)(r0 + rl) * NQKVD + (HH + KVD) + c0 + c4);
    lds_t[c4 + 0][rl] = f2bf(v.x * s.x);
    lds_t[c4 + 1][rl] = f2bf(v.y * s.y);
    lds_t[c4 + 2][rl] = f2bf(v.z * s.z);
    lds_t[c4 + 3][rl] = f2bf(v.w * s.w);
  }
  __syncthreads();
  const int cl = t >> 2;
  const int rs = (t & 3) * 16;
  union { unsigned short s[16]; uint4 q[2]; } o;
#pragma unroll
  for (int i = 0; i < 16; ++i) o.s[i] = lds_t[cl][rs + i];
  uint4* dst = (uint4*)(oVt + (size_t)(c0 + cl) * MR + r0 + rs);
  dst[0] = o.q[0]; dst[1] = o.q[1];
}

// O-proj epilogue: scale, fp32 out. grid(4, 2048), block 256.
__global__ void epi_o(const float* __restrict__ P, const float* __restrict__ sO,
                      float* __restrict__ out) {
  const int col = (blockIdx.x * 256 + threadIdx.x) * 4;
  const int row = blockIdx.y;
  float4 v = *(const float4*)(P + (size_t)row * HH + col);
  const float4 s = *(const float4*)(sO + col);
  v.x *= s.x; v.y *= s.y; v.z *= s.z; v.w *= s.w;
  *(float4*)(out + (size_t)row * HH + col) = v;
}

// ---------------- flash attention: 1 wave per (b, h, 16 q-rows), k-tiles of 32 ----------------
__global__ __launch_bounds__(64) void attn_kernel(
    const unsigned short* __restrict__ Q,   // [2048][4096]
    const unsigned short* __restrict__ K,   // [2048][1024]
    const unsigned short* __restrict__ Vt,  // [1024][2048]
    unsigned short* __restrict__ O) {       // [2048][4096]
  __shared__ unsigned short lds_p[16 * 32];
  const int lane = threadIdx.x;
  const int l15 = lane & 15, quad = lane >> 4;
  const int qb = blockIdx.x;
  const int h = blockIdx.y;
  const int b = blockIdx.z;
  const int kv = h >> 2;
  const int q0 = qb * 16;

  bf16x8 aq[4];
  const unsigned short* qbase = Q + (size_t)(b * SS + q0 + l15) * HH + h * HDD + quad * 8;
#pragma unroll
  for (int kk = 0; kk < 4; ++kk) aq[kk] = *(const bf16x8*)(qbase + kk * 32);

  f32x4 accO[8] = {};
  float m_run[4] = {-3.0e38f, -3.0e38f, -3.0e38f, -3.0e38f};
  float l_run[4] = {0.f, 0.f, 0.f, 0.f};

  const int nkt = qb / 2 + 1;
  for (int kt = 0; kt < nkt; ++kt) {
    const int k0 = kt * 32;
    f32x4 s0 = {}, s1 = {};
    const unsigned short* kb = K + (size_t)(b * SS + k0 + l15) * KVD + kv * HDD + quad * 8;
#pragma unroll
    for (int kk = 0; kk < 4; ++kk) {
      bf16x8 b0 = *(const bf16x8*)(kb + kk * 32);
      bf16x8 b1 = *(const bf16x8*)(kb + (size_t)16 * KVD + kk * 32);
      s0 = MFMA(aq[kk], b0, s0);
      s1 = MFMA(aq[kk], b1, s1);
    }
    float alpha[4], pw0[4], pw1[4];
#pragma unroll
    for (int r = 0; r < 4; ++r) {
      const int qrow = q0 + quad * 4 + r;
      float v0 = s0[r] * SCALE_F; if (k0 + l15 > qrow) v0 = -3.0e38f;
      float v1 = s1[r] * SCALE_F; if (k0 + 16 + l15 > qrow) v1 = -3.0e38f;
      float cm = fmaxf(v0, v1);
      cm = fmaxf(cm, __shfl_xor(cm, 1, 16));
      cm = fmaxf(cm, __shfl_xor(cm, 2, 16));
      cm = fmaxf(cm, __shfl_xor(cm, 4, 16));
      cm = fmaxf(cm, __shfl_xor(cm, 8, 16));
      const float mn = fmaxf(m_run[r], cm);
      const float al = __expf(m_run[r] - mn);
      const float p0 = __expf(v0 - mn);
      const float p1 = __expf(v1 - mn);
      float sum = p0 + p1;
      sum += __shfl_xor(sum, 1, 16);
      sum += __shfl_xor(sum, 2, 16);
      sum += __shfl_xor(sum, 4, 16);
      sum += __shfl_xor(sum, 8, 16);
      l_run[r] = l_run[r] * al + sum;
      m_run[r] = mn;
      alpha[r] = al;
      pw0[r] = p0; pw1[r] = p1;
    }
#pragma unroll
    for (int cb = 0; cb < 8; ++cb)
#pragma unroll
      for (int r = 0; r < 4; ++r) accO[cb][r] *= alpha[r];
    __syncthreads();
#pragma unroll
    for (int r = 0; r < 4; ++r) {
      lds_p[(quad * 4 + r) * 32 + l15] = f2bf(pw0[r]);
      lds_p[(quad * 4 + r) * 32 + 16 + l15] = f2bf(pw1[r]);
    }
    __syncthreads();
    bf16x8 ap = *(const bf16x8*)(lds_p + l15 * 32 + quad * 8);
    const unsigned short* vb = Vt + (size_t)(kv * HDD + l15) * MR + b * SS + k0 + quad * 8;
#pragma unroll
    for (int cb = 0; cb < 8; ++cb) {
      bf16x8 bv = *(const bf16x8*)(vb + (size_t)cb * 16 * MR);
      accO[cb] = MFMA(ap, bv, accO[cb]);
    }
  }
  unsigned short* ob = O + (size_t)(b * SS + q0 + quad * 4) * HH + h * HDD + l15;
#pragma unroll
  for (int cb = 0; cb < 8; ++cb)
#pragma unroll
    for (int r = 0; r < 4; ++r)
      ob[(size_t)r * HH + cb * 16] = f2bf(accO[cb][r] / l_run[r]);
}

extern "C" void kernel_launch(void* const* d_in, const int* in_sizes, int n_in,
                              void* d_out, int out_size, void* d_ws, size_t ws_size,
                              hipStream_t stream) {
  const float* x = (const float*)d_in[0];
  const int* wq = (const int*)d_in[2];
  const float* wqs = (const float*)d_in[3];
  const float* bq = (const float*)d_in[4];
  const int* wk = (const int*)d_in[5];
  const float* wks = (const float*)d_in[6];
  const float* bk = (const float*)d_in[7];
  const int* wv = (const int*)d_in[8];
  const float* wvs = (const float*)d_in[9];
  const int* wo = (const int*)d_in[10];
  const float* wos = (const float*)d_in[11];
  float* out = (float*)d_out;
  char* ws = (char*)d_ws;

  // workspace (MiB offsets), lifetime-packed, peak 112 MiB:
  unsigned short* x_bf    = (unsigned short*)(ws + (0ull  << 20)); // 16  [start, qkv-gemm]
  unsigned short* wqkv_bf = (unsigned short*)(ws + (16ull << 20)); // 48  [start, qkv-gemm]
  float*          P_qkv   = (float*)         (ws + (64ull << 20)); // 48  [qkv-gemm, epis]
  unsigned short* q_bf    = (unsigned short*)(ws + (0ull  << 20)); // 16  [epi, attn]  (over x_bf)
  unsigned short* k_bf    = (unsigned short*)(ws + (16ull << 20)); // 4   [epi, attn]  (over wqkv)
  unsigned short* v_t     = (unsigned short*)(ws + (20ull << 20)); // 4   [epi, attn]
  unsigned short* wo_bf   = (unsigned short*)(ws + (24ull << 20)); // 32  [cvt, o-gemm]
  unsigned short* a_bf    = (unsigned short*)(ws + (64ull << 20)); // 16  [attn, o-gemm] (over P_qkv)
  float*          P_o     = (float*)         (ws + (80ull << 20)); // 32  [o-gemm, epi_o]
  if (ws_size < (112ull << 20)) return;

  cvt_f32_bf16<<<8192, 256, 0, stream>>>(x, x_bf, MR * HH / 4);
  cvt_i32_bf16<<<16384, 256, 0, stream>>>(wq, wqkv_bf, HH * HH / 4);
  cvt_i32_bf16<<<4096, 256, 0, stream>>>(wk, wqkv_bf + (size_t)HH * HH, KVD * HH / 4);
  cvt_i32_bf16<<<4096, 256, 0, stream>>>(wv, wqkv_bf + (size_t)(HH + KVD) * HH, KVD * HH / 4);

  hipMemsetAsync(P_qkv, 0, (size_t)MR * NQKVD * 4, stream);
  gemm_splitk<<<dim3(NQKVD / 128, MR / 128, 2), 256, 0, stream>>>(x_bf, wqkv_bf, P_qkv, NQKVD);

  cvt_i32_bf16<<<16384, 256, 0, stream>>>(wo, wo_bf, HH * HH / 4);  // wqkv_bf dead now

  epi_qk<<<dim3(5, MR), 256, 0, stream>>>(P_qkv, wqs, bq, wks, bk, q_bf, k_bf);
  epi_v<<<dim3(16, 32), 256, 0, stream>>>(P_qkv, wvs, v_t);

  attn_kernel<<<dim3(SS / 16, NHH, BB), 64, 0, stream>>>(q_bf, k_bf, v_t, a_bf);

  hipMemsetAsync(P_o, 0, (size_t)MR * HH * 4, stream);
  gemm_splitk<<<dim3(HH / 128, MR / 128, 2), 256, 0, stream>>>(a_bf, wo_bf, P_o, HH);
  epi_o<<<dim3(4, MR), 256, 0, stream>>>(P_o, wos, out);
}

// Round 3
// 676.519 us; speedup vs baseline: 1.2192x; 1.2192x over previous
//
#include <hip/hip_runtime.h>
#include <math.h>

// Problem constants
#define BB   2
#define SS   1024
#define HH   4096
#define NHH  32
#define NKVV 8
#define HDD  128
#define MR   2048   // B*S
#define KVD  1024   // NKV*HD
#define NQKVD 6144  // H + 2*KVD
#define KD   4096
#define KHALF 2048
#define SCALE_F 0.08838834764831845f  // 1/sqrt(128)

typedef __attribute__((ext_vector_type(8))) short bf16x8;
typedef __attribute__((ext_vector_type(4))) float f32x4;

#define MFMA(a, b, c) __builtin_amdgcn_mfma_f32_16x16x32_bf16((a), (b), (c), 0, 0, 0)

__device__ __forceinline__ unsigned short f2bf(float f) {
  union { float f; unsigned u; } v; v.f = f;
  return (unsigned short)((v.u + 0x7fffu + ((v.u >> 16) & 1u)) >> 16);
}
__device__ __forceinline__ unsigned short f2h(float f) {
  union { _Float16 h; unsigned short s; } v; v.h = (_Float16)f; return v.s;
}
__device__ __forceinline__ float h2f(unsigned short s) {
  union { unsigned short s; _Float16 h; } v; v.s = s; return (float)v.h;
}
// load 4 fp16 -> float4
__device__ __forceinline__ float4 ld4h(const unsigned short* p) {
  uint2 d = *(const uint2*)p;
  float4 r;
  r.x = h2f((unsigned short)(d.x & 0xffff)); r.y = h2f((unsigned short)(d.x >> 16));
  r.z = h2f((unsigned short)(d.y & 0xffff)); r.w = h2f((unsigned short)(d.y >> 16));
  return r;
}

__device__ __forceinline__ void gload_lds16(const void* g, void* l) {
  __builtin_amdgcn_global_load_lds(
      (const __attribute__((address_space(1))) void*)g,
      (__attribute__((address_space(3))) void*)l, 16, 0, 0);
}

// ---------------- conversions ----------------
__global__ void cvt_f32_bf16(const float* __restrict__ in, unsigned short* __restrict__ out, int n4) {
  int i = blockIdx.x * blockDim.x + threadIdx.x;
  if (i >= n4) return;
  float4 v = ((const float4*)in)[i];
  union { unsigned short s[4]; uint2 d; } o;
  o.s[0] = f2bf(v.x); o.s[1] = f2bf(v.y); o.s[2] = f2bf(v.z); o.s[3] = f2bf(v.w);
  ((uint2*)out)[i] = o.d;
}

__global__ void cvt_i32_bf16(const int* __restrict__ in, unsigned short* __restrict__ out, int n4) {
  int i = blockIdx.x * blockDim.x + threadIdx.x;
  if (i >= n4) return;
  int4 v = ((const int4*)in)[i];
  union { unsigned short s[4]; uint2 d; } o;
  o.s[0] = f2bf((float)v.x); o.s[1] = f2bf((float)v.y);
  o.s[2] = f2bf((float)v.z); o.s[3] = f2bf((float)v.w);
  ((uint2*)out)[i] = o.d;
}

// ---------------- split-K GEMM: P[kz] = A[M,kz-half] * W[N,kz-half]^T ----------------
// 128x128 tile, BK=32. fp16 partials (no atomics, no memset); epilogues sum the 2 halves.
__global__ __launch_bounds__(256) void gemm_splitk(
    const unsigned short* __restrict__ A, const unsigned short* __restrict__ W,
    unsigned short* __restrict__ P, int N) {
  __shared__ unsigned short ldsA[128 * 32];
  __shared__ unsigned short ldsB[128 * 32];
  const int t = threadIdx.x;
  const int lane = t & 63;
  const int w = t >> 6;
  const int wr = w & 1, wc = w >> 1;
  const int l15 = lane & 15, quad = lane >> 4;
  const int bm = blockIdx.y, bn = blockIdx.x, kz = blockIdx.z;

  const int srow = t >> 2;
  const int scol = (t & 3) * 8;
  const unsigned short* gA = A + (size_t)(bm * 128 + srow) * KD + scol + kz * KHALF;
  const unsigned short* gW = W + (size_t)(bn * 128 + srow) * KD + scol + kz * KHALF;
  unsigned short* lA = ldsA + t * 8;  // wave base + lane*16 bytes (global_load_lds layout rule)
  unsigned short* lB = ldsB + t * 8;

  f32x4 acc[4][4] = {};

  for (int k0 = 0; k0 < KHALF; k0 += 32) {
    __syncthreads();
    gload_lds16(gA + k0, lA);
    gload_lds16(gA + (size_t)64 * KD + k0, lA + 2048);
    gload_lds16(gW + k0, lB);
    gload_lds16(gW + (size_t)64 * KD + k0, lB + 2048);
    __syncthreads();
    bf16x8 af[4], bfr[4];
#pragma unroll
    for (int mi = 0; mi < 4; ++mi)
      af[mi] = *(const bf16x8*)(ldsA + (wr * 64 + mi * 16 + l15) * 32 + quad * 8);
#pragma unroll
    for (int ni = 0; ni < 4; ++ni)
      bfr[ni] = *(const bf16x8*)(ldsB + (wc * 64 + ni * 16 + l15) * 32 + quad * 8);
#pragma unroll
    for (int mi = 0; mi < 4; ++mi)
#pragma unroll
      for (int ni = 0; ni < 4; ++ni)
        acc[mi][ni] = MFMA(af[mi], bfr[ni], acc[mi][ni]);
  }

  // C/D layout: row = quad*4 + r, col = lane&15 (m89-verified)
  unsigned short* Pz = P + (size_t)kz * MR * N;
  const int row0 = bm * 128 + wr * 64 + quad * 4;
  const int col0 = bn * 128 + wc * 64 + l15;
#pragma unroll
  for (int mi = 0; mi < 4; ++mi)
#pragma unroll
    for (int ni = 0; ni < 4; ++ni)
#pragma unroll
      for (int r = 0; r < 4; ++r)
        Pz[(size_t)(row0 + mi * 16 + r) * N + col0 + ni * 16] = f2h(acc[mi][ni][r]);
}

// ---------------- epilogues (sum 2 fp16 partial halves) ----------------
// Q/K columns: scale+bias -> bf16. grid(5, 2048), block 256, 4 cols/thread.
__global__ void epi_qk(const unsigned short* __restrict__ P0, const unsigned short* __restrict__ P1,
                       const float* __restrict__ sQ, const float* __restrict__ bQ,
                       const float* __restrict__ sK, const float* __restrict__ bK,
                       unsigned short* __restrict__ oQ, unsigned short* __restrict__ oK) {
  const int col = (blockIdx.x * 256 + threadIdx.x) * 4;
  const int row = blockIdx.y;
  const size_t off = (size_t)row * NQKVD + col;
  float4 a = ld4h(P0 + off), b2 = ld4h(P1 + off);
  float4 v = make_float4(a.x + b2.x, a.y + b2.y, a.z + b2.z, a.w + b2.w);
  union { unsigned short s[4]; uint2 d; } o;
  if (col < HH) {
    const float4 s = *(const float4*)(sQ + col);
    const float4 b = *(const float4*)(bQ + col);
    o.s[0] = f2bf(v.x * s.x + b.x); o.s[1] = f2bf(v.y * s.y + b.y);
    o.s[2] = f2bf(v.z * s.z + b.z); o.s[3] = f2bf(v.w * s.w + b.w);
    *(uint2*)(oQ + (size_t)row * HH + col) = o.d;
  } else {
    const int c = col - HH;
    const float4 s = *(const float4*)(sK + c);
    const float4 b = *(const float4*)(bK + c);
    o.s[0] = f2bf(v.x * s.x + b.x); o.s[1] = f2bf(v.y * s.y + b.y);
    o.s[2] = f2bf(v.z * s.z + b.z); o.s[3] = f2bf(v.w * s.w + b.w);
    *(uint2*)(oK + (size_t)row * KVD + c) = o.d;
  }
}

// V columns: scale -> bf16, TRANSPOSED via LDS 64x64 tile. grid(16, 32), block 256.
__global__ void epi_v(const unsigned short* __restrict__ P0, const unsigned short* __restrict__ P1,
                      const float* __restrict__ sV, unsigned short* __restrict__ oVt) {
  __shared__ unsigned short lds_t[64][65];
  const int t = threadIdx.x;
  const int c0 = blockIdx.x * 64;
  const int r0 = blockIdx.y * 64;
  const int c4 = (t & 15) * 4;
  const float4 s = *(const float4*)(sV + c0 + c4);
#pragma unroll
  for (int rr = 0; rr < 4; ++rr) {
    const int rl = (t >> 4) * 4 + rr;
    const size_t off = (size_t)(r0 + rl) * NQKVD + (HH + KVD) + c0 + c4;
    float4 a = ld4h(P0 + off), b = ld4h(P1 + off);
    lds_t[c4 + 0][rl] = f2bf((a.x + b.x) * s.x);
    lds_t[c4 + 1][rl] = f2bf((a.y + b.y) * s.y);
    lds_t[c4 + 2][rl] = f2bf((a.z + b.z) * s.z);
    lds_t[c4 + 3][rl] = f2bf((a.w + b.w) * s.w);
  }
  __syncthreads();
  const int cl = t >> 2;
  const int rs = (t & 3) * 16;
  union { unsigned short s[16]; uint4 q[2]; } o;
#pragma unroll
  for (int i = 0; i < 16; ++i) o.s[i] = lds_t[cl][rs + i];
  uint4* dst = (uint4*)(oVt + (size_t)(c0 + cl) * MR + r0 + rs);
  dst[0] = o.q[0]; dst[1] = o.q[1];
}

// O-proj epilogue: scale -> fp32 out. grid(4, 2048), block 256.
__global__ void epi_o(const unsigned short* __restrict__ P0, const unsigned short* __restrict__ P1,
                      const float* __restrict__ sO, float* __restrict__ out) {
  const int col = (blockIdx.x * 256 + threadIdx.x) * 4;
  const int row = blockIdx.y;
  const size_t off = (size_t)row * HH + col;
  float4 a = ld4h(P0 + off), b = ld4h(P1 + off);
  const float4 s = *(const float4*)(sO + col);
  float4 v = make_float4((a.x + b.x) * s.x, (a.y + b.y) * s.y,
                         (a.z + b.z) * s.z, (a.w + b.w) * s.w);
  *(float4*)(out + off) = v;
}

// ---------------- flash attention v2: transposed scores S^T = K*Q^T ----------------
// 1 wave per (b, h, 16 q-rows); k-tiles of 64. Softmax k-axis lies along registers:
// 15 VALU + 2 shfls per reduction instead of 32 shfls/32k-tile. No __syncthreads
// (single wave; same-wave DS ordering + compiler lgkmcnt handles the P round trip).
__global__ __launch_bounds__(64) void attn_kernel(
    const unsigned short* __restrict__ Q,   // [2048][4096]
    const unsigned short* __restrict__ K,   // [2048][1024]
    const unsigned short* __restrict__ Vt,  // [1024][2048]
    unsigned short* __restrict__ O) {       // [2048][4096]
  __shared__ unsigned short lds_p[16 * 80];  // [q=16][k=64 pad->80] (b128-aligned reads)
  const int lane = threadIdx.x;
  const int l15 = lane & 15, quad = lane >> 4;
  const int qb = 63 - blockIdx.x;  // heavy blocks first (causal imbalance)
  const int h = blockIdx.y;
  const int b = blockIdx.z;
  const int kv = h >> 2;
  const int q0 = qb * 16;
  const int q = q0 + l15;  // this lane's softmax column

  // Q as B-frags: B[k=hd][n=q]: lane holds Q[q0+l15][kk*32 + quad*8 + j]
  bf16x8 bq[4];
  const unsigned short* qbase = Q + (size_t)(b * SS + q0 + l15) * HH + h * HDD + quad * 8;
#pragma unroll
  for (int kk = 0; kk < 4; ++kk) bq[kk] = *(const bf16x8*)(qbase + kk * 32);

  f32x4 accO[8] = {};
  float m_run = -1e30f, l_run = 0.f;  // state for column q (replicated across quads)

  const int nkt = qb / 4 + 1;  // k <= q0+15
  for (int kt = 0; kt < nkt; ++kt) {
    const int k0 = kt * 64;
    // K as A-frags: A[m=k-local][hd]: lane holds K[k0+mf*16+l15][kk*32+quad*8+j]
    const unsigned short* kb = K + (size_t)(b * SS + k0 + l15) * KVD + kv * HDD + quad * 8;
    bf16x8 ka[4][4];
#pragma unroll
    for (int mf = 0; mf < 4; ++mf)
#pragma unroll
      for (int kk = 0; kk < 4; ++kk)
        ka[mf][kk] = *(const bf16x8*)(kb + (size_t)mf * 16 * KVD + kk * 32);
    f32x4 st[4] = {};  // S^T: row = k-local = mf*16+quad*4+r, col = q = l15
#pragma unroll
    for (int kk = 0; kk < 4; ++kk)
#pragma unroll
      for (int mf = 0; mf < 4; ++mf)
        st[mf] = MFMA(ka[mf][kk], bq[kk], st[mf]);

    // mask + scale; column max over 16 regs + 2 shfls
    float p[4][4];
    float cm = -1e30f;
#pragma unroll
    for (int mf = 0; mf < 4; ++mf)
#pragma unroll
      for (int r = 0; r < 4; ++r) {
        const int k = k0 + mf * 16 + quad * 4 + r;
        float v = st[mf][r] * SCALE_F;
        if (k > q) v = -1e30f;
        p[mf][r] = v;
        cm = fmaxf(cm, v);
      }
    cm = fmaxf(cm, __shfl_xor(cm, 16));
    cm = fmaxf(cm, __shfl_xor(cm, 32));
    const float mn = fmaxf(m_run, cm);
    const float al = __expf(m_run - mn);
    float sum = 0.f;
#pragma unroll
    for (int mf = 0; mf < 4; ++mf)
#pragma unroll
      for (int r = 0; r < 4; ++r) {
        const float e = __expf(p[mf][r] - mn);
        p[mf][r] = e;
        sum += e;
      }
    sum += __shfl_xor(sum, 16);
    sum += __shfl_xor(sum, 32);
    l_run = l_run * al + sum;
    m_run = mn;
    // alpha for accO rows (q = quad*4+r): lanes 0..15 hold all 16 columns' alpha
    float af4[4];
#pragma unroll
    for (int r = 0; r < 4; ++r) af4[r] = __shfl(al, quad * 4 + r);
#pragma unroll
    for (int cb = 0; cb < 8; ++cb)
#pragma unroll
      for (int r = 0; r < 4; ++r) accO[cb][r] *= af4[r];

    // P^T (C-layout) -> LDS [q][k] -> A-frags A[q=l15][k=quad*8+j]
#pragma unroll
    for (int mf = 0; mf < 4; ++mf)
#pragma unroll
      for (int r = 0; r < 4; ++r)
        lds_p[l15 * 80 + mf * 16 + quad * 4 + r] = f2bf(p[mf][r]);
    bf16x8 ap0 = *(const bf16x8*)(lds_p + l15 * 80 + quad * 8);
    bf16x8 ap1 = *(const bf16x8*)(lds_p + l15 * 80 + 32 + quad * 8);

    // V B-frags from Vt: B[k=s][n=hd]: lane holds Vt[kv*128+cb*16+l15][k0+kc*32+quad*8+j]
    const unsigned short* vb = Vt + (size_t)(kv * HDD + l15) * MR + b * SS + k0 + quad * 8;
#pragma unroll
    for (int cb = 0; cb < 8; ++cb) {
      bf16x8 bv0 = *(const bf16x8*)(vb + (size_t)cb * 16 * MR);
      bf16x8 bv1 = *(const bf16x8*)(vb + (size_t)cb * 16 * MR + 32);
      accO[cb] = MFMA(ap0, bv0, accO[cb]);
      accO[cb] = MFMA(ap1, bv1, accO[cb]);
    }
  }
  // epilogue: row q = quad*4+r needs l for that column
  float lr[4];
#pragma unroll
  for (int r = 0; r < 4; ++r) lr[r] = __shfl(l_run, quad * 4 + r);
  unsigned short* ob = O + (size_t)(b * SS + q0 + quad * 4) * HH + h * HDD + l15;
#pragma unroll
  for (int cb = 0; cb < 8; ++cb)
#pragma unroll
    for (int r = 0; r < 4; ++r)
      ob[(size_t)r * HH + cb * 16] = f2bf(accO[cb][r] / lr[r]);
}

extern "C" void kernel_launch(void* const* d_in, const int* in_sizes, int n_in,
                              void* d_out, int out_size, void* d_ws, size_t ws_size,
                              hipStream_t stream) {
  const float* x = (const float*)d_in[0];
  const int* wq = (const int*)d_in[2];
  const float* wqs = (const float*)d_in[3];
  const float* bq = (const float*)d_in[4];
  const int* wk = (const int*)d_in[5];
  const float* wks = (const float*)d_in[6];
  const float* bk = (const float*)d_in[7];
  const int* wv = (const int*)d_in[8];
  const float* wvs = (const float*)d_in[9];
  const int* wo = (const int*)d_in[10];
  const float* wos = (const float*)d_in[11];
  float* out = (float*)d_out;
  char* ws = (char*)d_ws;

  // workspace (MiB offsets), lifetime-packed, peak 112 MiB:
  unsigned short* x_bf    = (unsigned short*)(ws + (0ull  << 20)); // 16  [cvt, qkv-gemm]
  unsigned short* wqkv_bf = (unsigned short*)(ws + (16ull << 20)); // 48  [cvt, qkv-gemm]
  unsigned short* Pq0     = (unsigned short*)(ws + (64ull << 20)); // 24  fp16 [gemm, epis]
  unsigned short* Pq1     = (unsigned short*)(ws + (88ull << 20)); // 24  fp16
  unsigned short* q_bf    = (unsigned short*)(ws + (0ull  << 20)); // 16  [epi, attn] (over x_bf)
  unsigned short* k_bf    = (unsigned short*)(ws + (16ull << 20)); // 4   [epi, attn] (over wqkv head)
  unsigned short* v_t     = (unsigned short*)(ws + (20ull << 20)); // 4   [epi, attn]
  unsigned short* wo_bf   = (unsigned short*)(ws + (24ull << 20)); // 32  [cvt(after qkv-gemm), o-gemm]
  unsigned short* a_bf    = (unsigned short*)(ws + (64ull << 20)); // 16  [attn, o-gemm] (over Pq0)
  unsigned short* Po0     = (unsigned short*)(ws + (80ull << 20)); // 16  fp16 [o-gemm, epi_o]
  unsigned short* Po1     = (unsigned short*)(ws + (96ull << 20)); // 16  fp16
  if (ws_size < (112ull << 20)) return;

  cvt_f32_bf16<<<8192, 256, 0, stream>>>(x, x_bf, MR * HH / 4);
  cvt_i32_bf16<<<16384, 256, 0, stream>>>(wq, wqkv_bf, HH * HH / 4);
  cvt_i32_bf16<<<4096, 256, 0, stream>>>(wk, wqkv_bf + (size_t)HH * HH, KVD * HH / 4);
  cvt_i32_bf16<<<4096, 256, 0, stream>>>(wv, wqkv_bf + (size_t)(HH + KVD) * HH, KVD * HH / 4);

  gemm_splitk<<<dim3(NQKVD / 128, MR / 128, 2), 256, 0, stream>>>(x_bf, wqkv_bf, Pq0, NQKVD);

  cvt_i32_bf16<<<16384, 256, 0, stream>>>(wo, wo_bf, HH * HH / 4);  // wqkv_bf dead now

  epi_qk<<<dim3(5, MR), 256, 0, stream>>>(Pq0, Pq1, wqs, bq, wks, bk, q_bf, k_bf);
  epi_v<<<dim3(16, 32), 256, 0, stream>>>(Pq0, Pq1, wvs, v_t);

  attn_kernel<<<dim3(SS / 16, NHH, BB), 64, 0, stream>>>(q_bf, k_bf, v_t, a_bf);

  gemm_splitk<<<dim3(HH / 128, MR / 128, 2), 256, 0, stream>>>(a_bf, wo_bf, Po0, HH);
  epi_o<<<dim3(4, MR), 256, 0, stream>>>(Po0, Po1, wos, out);
}

// Round 4
// 529.584 us; speedup vs baseline: 1.5575x; 1.2775x over previous
//
#include <hip/hip_runtime.h>
#include <math.h>

// Problem constants
#define BB   2
#define SS   1024
#define HH   4096
#define NHH  32
#define NKVV 8
#define HDD  128
#define MR   2048   // B*S
#define KVD  1024   // NKV*HD
#define NQKVD 6144  // H + 2*KVD
#define KD   4096
#define KHALF 2048
#define SCALE_F 0.08838834764831845f  // 1/sqrt(128)

typedef __attribute__((ext_vector_type(8))) short bf16x8;
typedef __attribute__((ext_vector_type(4))) float f32x4;

#define MFMA(a, b, c) __builtin_amdgcn_mfma_f32_16x16x32_bf16((a), (b), (c), 0, 0, 0)

__device__ __forceinline__ unsigned short f2bf(float f) {
  union { float f; unsigned u; } v; v.f = f;
  return (unsigned short)((v.u + 0x7fffu + ((v.u >> 16) & 1u)) >> 16);
}
__device__ __forceinline__ unsigned short f2h(float f) {
  union { _Float16 h; unsigned short s; } v; v.h = (_Float16)f; return v.s;
}
__device__ __forceinline__ float h2f(unsigned short s) {
  union { unsigned short s; _Float16 h; } v; v.s = s; return (float)v.h;
}
__device__ __forceinline__ float4 ld4h(const unsigned short* p) {
  uint2 d = *(const uint2*)p;
  float4 r;
  r.x = h2f((unsigned short)(d.x & 0xffff)); r.y = h2f((unsigned short)(d.x >> 16));
  r.z = h2f((unsigned short)(d.y & 0xffff)); r.w = h2f((unsigned short)(d.y >> 16));
  return r;
}

__device__ __forceinline__ void gload_lds16(const void* g, void* l) {
  __builtin_amdgcn_global_load_lds(
      (const __attribute__((address_space(1))) void*)g,
      (__attribute__((address_space(3))) void*)l, 16, 0, 0);
}

// ---------------- conversions ----------------
__global__ void cvt_f32_bf16(const float* __restrict__ in, unsigned short* __restrict__ out, int n4) {
  int i = blockIdx.x * blockDim.x + threadIdx.x;
  if (i >= n4) return;
  float4 v = ((const float4*)in)[i];
  union { unsigned short s[4]; uint2 d; } o;
  o.s[0] = f2bf(v.x); o.s[1] = f2bf(v.y); o.s[2] = f2bf(v.z); o.s[3] = f2bf(v.w);
  ((uint2*)out)[i] = o.d;
}

__global__ void cvt_i32_bf16(const int* __restrict__ in, unsigned short* __restrict__ out, int n4) {
  int i = blockIdx.x * blockDim.x + threadIdx.x;
  if (i >= n4) return;
  int4 v = ((const int4*)in)[i];
  union { unsigned short s[4]; uint2 d; } o;
  o.s[0] = f2bf((float)v.x); o.s[1] = f2bf((float)v.y);
  o.s[2] = f2bf((float)v.z); o.s[3] = f2bf((float)v.w);
  ((uint2*)out)[i] = o.d;
}

// ---------------- split-K GEMM: P[kz] = A[M,kz-half] * W[N,kz-half]^T ----------------
// 128x128 tile, BK=32. fp16 partials (no atomics, no memset); epilogues sum the 2 halves.
__global__ __launch_bounds__(256) void gemm_splitk(
    const unsigned short* __restrict__ A, const unsigned short* __restrict__ W,
    unsigned short* __restrict__ P, int N) {
  __shared__ unsigned short ldsA[128 * 32];
  __shared__ unsigned short ldsB[128 * 32];
  const int t = threadIdx.x;
  const int lane = t & 63;
  const int w = t >> 6;
  const int wr = w & 1, wc = w >> 1;
  const int l15 = lane & 15, quad = lane >> 4;
  const int bm = blockIdx.y, bn = blockIdx.x, kz = blockIdx.z;

  const int srow = t >> 2;
  const int scol = (t & 3) * 8;
  const unsigned short* gA = A + (size_t)(bm * 128 + srow) * KD + scol + kz * KHALF;
  const unsigned short* gW = W + (size_t)(bn * 128 + srow) * KD + scol + kz * KHALF;
  unsigned short* lA = ldsA + t * 8;
  unsigned short* lB = ldsB + t * 8;

  f32x4 acc[4][4] = {};

  for (int k0 = 0; k0 < KHALF; k0 += 32) {
    __syncthreads();
    gload_lds16(gA + k0, lA);
    gload_lds16(gA + (size_t)64 * KD + k0, lA + 2048);
    gload_lds16(gW + k0, lB);
    gload_lds16(gW + (size_t)64 * KD + k0, lB + 2048);
    __syncthreads();
    bf16x8 af[4], bfr[4];
#pragma unroll
    for (int mi = 0; mi < 4; ++mi)
      af[mi] = *(const bf16x8*)(ldsA + (wr * 64 + mi * 16 + l15) * 32 + quad * 8);
#pragma unroll
    for (int ni = 0; ni < 4; ++ni)
      bfr[ni] = *(const bf16x8*)(ldsB + (wc * 64 + ni * 16 + l15) * 32 + quad * 8);
#pragma unroll
    for (int mi = 0; mi < 4; ++mi)
#pragma unroll
      for (int ni = 0; ni < 4; ++ni)
        acc[mi][ni] = MFMA(af[mi], bfr[ni], acc[mi][ni]);
  }

  unsigned short* Pz = P + (size_t)kz * MR * N;
  const int row0 = bm * 128 + wr * 64 + quad * 4;
  const int col0 = bn * 128 + wc * 64 + l15;
#pragma unroll
  for (int mi = 0; mi < 4; ++mi)
#pragma unroll
    for (int ni = 0; ni < 4; ++ni)
#pragma unroll
      for (int r = 0; r < 4; ++r)
        Pz[(size_t)(row0 + mi * 16 + r) * N + col0 + ni * 16] = f2h(acc[mi][ni][r]);
}

// ---------------- epilogues (sum 2 fp16 partial halves) ----------------
__global__ void epi_qk(const unsigned short* __restrict__ P0, const unsigned short* __restrict__ P1,
                       const float* __restrict__ sQ, const float* __restrict__ bQ,
                       const float* __restrict__ sK, const float* __restrict__ bK,
                       unsigned short* __restrict__ oQ, unsigned short* __restrict__ oK) {
  const int col = (blockIdx.x * 256 + threadIdx.x) * 4;
  const int row = blockIdx.y;
  const size_t off = (size_t)row * NQKVD + col;
  float4 a = ld4h(P0 + off), b2 = ld4h(P1 + off);
  float4 v = make_float4(a.x + b2.x, a.y + b2.y, a.z + b2.z, a.w + b2.w);
  union { unsigned short s[4]; uint2 d; } o;
  if (col < HH) {
    const float4 s = *(const float4*)(sQ + col);
    const float4 b = *(const float4*)(bQ + col);
    o.s[0] = f2bf(v.x * s.x + b.x); o.s[1] = f2bf(v.y * s.y + b.y);
    o.s[2] = f2bf(v.z * s.z + b.z); o.s[3] = f2bf(v.w * s.w + b.w);
    *(uint2*)(oQ + (size_t)row * HH + col) = o.d;
  } else {
    const int c = col - HH;
    const float4 s = *(const float4*)(sK + c);
    const float4 b = *(const float4*)(bK + c);
    o.s[0] = f2bf(v.x * s.x + b.x); o.s[1] = f2bf(v.y * s.y + b.y);
    o.s[2] = f2bf(v.z * s.z + b.z); o.s[3] = f2bf(v.w * s.w + b.w);
    *(uint2*)(oK + (size_t)row * KVD + c) = o.d;
  }
}

__global__ void epi_v(const unsigned short* __restrict__ P0, const unsigned short* __restrict__ P1,
                      const float* __restrict__ sV, unsigned short* __restrict__ oVt) {
  __shared__ unsigned short lds_t[64][65];
  const int t = threadIdx.x;
  const int c0 = blockIdx.x * 64;
  const int r0 = blockIdx.y * 64;
  const int c4 = (t & 15) * 4;
  const float4 s = *(const float4*)(sV + c0 + c4);
#pragma unroll
  for (int rr = 0; rr < 4; ++rr) {
    const int rl = (t >> 4) * 4 + rr;
    const size_t off = (size_t)(r0 + rl) * NQKVD + (HH + KVD) + c0 + c4;
    float4 a = ld4h(P0 + off), b = ld4h(P1 + off);
    lds_t[c4 + 0][rl] = f2bf((a.x + b.x) * s.x);
    lds_t[c4 + 1][rl] = f2bf((a.y + b.y) * s.y);
    lds_t[c4 + 2][rl] = f2bf((a.z + b.z) * s.z);
    lds_t[c4 + 3][rl] = f2bf((a.w + b.w) * s.w);
  }
  __syncthreads();
  const int cl = t >> 2;
  const int rs = (t & 3) * 16;
  union { unsigned short s[16]; uint4 q[2]; } o;
#pragma unroll
  for (int i = 0; i < 16; ++i) o.s[i] = lds_t[cl][rs + i];
  uint4* dst = (uint4*)(oVt + (size_t)(c0 + cl) * MR + r0 + rs);
  dst[0] = o.q[0]; dst[1] = o.q[1];
}

__global__ void epi_o(const unsigned short* __restrict__ P0, const unsigned short* __restrict__ P1,
                      const float* __restrict__ sO, float* __restrict__ out) {
  const int col = (blockIdx.x * 256 + threadIdx.x) * 4;
  const int row = blockIdx.y;
  const size_t off = (size_t)row * HH + col;
  float4 a = ld4h(P0 + off), b = ld4h(P1 + off);
  const float4 s = *(const float4*)(sO + col);
  float4 v = make_float4((a.x + b.x) * s.x, (a.y + b.y) * s.y,
                         (a.z + b.z) * s.z, (a.w + b.w) * s.w);
  *(float4*)(out + off) = v;
}

// ---------------- flash attention v3: 4-wave blocks, 64-row Q tile, LDS-staged K/V ----------------
// Block = (b, h, qt) with 64 q-rows; wave wv owns rows [qt*64+wv*16, +16).
// Per 64-k tile: stage K (kk-slab [4][64][32]) + Vt (kc-slab [2][128][32]) via
// global_load_lds, then each wave: 16 QK MFMA (S^T = K*Q^T, softmax axis in regs),
// online softmax, P->LDS->A-frag, 16 PV MFMA. LDS 44 KB -> 3 blocks/CU.
__global__ __launch_bounds__(256, 3) void attn_kernel(
    const unsigned short* __restrict__ Q,   // [2048][4096]
    const unsigned short* __restrict__ K,   // [2048][1024]
    const unsigned short* __restrict__ Vt,  // [1024][2048]
    unsigned short* __restrict__ O) {       // [2048][4096]
  __shared__ unsigned short ldsK[4 * 64 * 32];   // [kk][krow][32]  16 KB
  __shared__ unsigned short ldsV[2 * 128 * 32];  // [kc][hd][32]    16 KB
  __shared__ unsigned short ldsP[4][16 * 88];    // per-wave P tile 11 KB
  const int t = threadIdx.x;
  const int lane = t & 63;
  const int wv = t >> 6;
  const int l15 = lane & 15, quad = lane >> 4;
  const int qt = 15 - blockIdx.x;  // heavy-first
  const int h = blockIdx.y;
  const int b = blockIdx.z;
  const int kv = h >> 2;
  const int q0w = qt * 64 + wv * 16;
  const int q = q0w + l15;  // this lane's softmax column

  // Q as B-frags: lane holds Q[q0w+l15][h*128 + kk*32 + quad*8 + j]
  bf16x8 bq[4];
  const unsigned short* qbase = Q + (size_t)(b * SS + q0w + l15) * HH + h * HDD + quad * 8;
#pragma unroll
  for (int kk = 0; kk < 4; ++kk) bq[kk] = *(const bf16x8*)(qbase + kk * 32);

  // staging bases (wave wv stages K kk-slab wv, and V hd-rows [wv*32, wv*32+32))
  const unsigned short* gK = K + (size_t)(b * SS) * KVD + kv * HDD + wv * 32 + (lane & 3) * 8;
  const unsigned short* gV = Vt + (size_t)(kv * HDD + wv * 32 + (lane >> 2)) * MR + b * SS + (lane & 3) * 8;
  unsigned short* lK = ldsK + wv * 2048 + lane * 8;
  unsigned short* lV = ldsV + (size_t)wv * 32 * 32 + lane * 8;
  unsigned short* lp = ldsP[wv];

  f32x4 accO[8] = {};
  float m_run = -1e30f, l_run = 0.f;

  for (int kt = 0; kt <= qt; ++kt) {
    const int k0 = kt * 64;
    __syncthreads();  // all waves done reading previous K/V tiles
#pragma unroll
    for (int j = 0; j < 4; ++j)
      gload_lds16(gK + (size_t)(k0 + j * 16 + (lane >> 2)) * KVD, lK + j * 512);
#pragma unroll
    for (int kc = 0; kc < 2; ++kc)
#pragma unroll
      for (int j = 0; j < 2; ++j)
        gload_lds16(gV + (size_t)j * 16 * MR + k0 + kc * 32,
                    lV + kc * 4096 + j * 512);
    __syncthreads();  // staging complete

    // QK^T (S^T): st[mf] row = k_local = mf*16 + quad*4 + r, col = q = l15
    f32x4 st[4] = {};
#pragma unroll
    for (int kk = 0; kk < 4; ++kk)
#pragma unroll
      for (int mf = 0; mf < 4; ++mf) {
        bf16x8 af = *(const bf16x8*)(ldsK + kk * 2048 + (mf * 16 + l15) * 32 + quad * 8);
        st[mf] = MFMA(af, bq[kk], st[mf]);
      }

    // mask + scale; column max: 16 regs + 2 shfls
    float p[4][4];
    float cm = -1e30f;
#pragma unroll
    for (int mf = 0; mf < 4; ++mf)
#pragma unroll
      for (int r = 0; r < 4; ++r) {
        const int k = k0 + mf * 16 + quad * 4 + r;
        float v = st[mf][r] * SCALE_F;
        if (k > q) v = -1e30f;
        p[mf][r] = v;
        cm = fmaxf(cm, v);
      }
    cm = fmaxf(cm, __shfl_xor(cm, 16));
    cm = fmaxf(cm, __shfl_xor(cm, 32));
    const float mn = fmaxf(m_run, cm);
    const float al = __expf(m_run - mn);
    float sum = 0.f;
#pragma unroll
    for (int mf = 0; mf < 4; ++mf)
#pragma unroll
      for (int r = 0; r < 4; ++r) {
        const float e = __expf(p[mf][r] - mn);
        p[mf][r] = e;
        sum += e;
      }
    sum += __shfl_xor(sum, 16);
    sum += __shfl_xor(sum, 32);
    l_run = l_run * al + sum;
    m_run = mn;
    float af4[4];
#pragma unroll
    for (int r = 0; r < 4; ++r) af4[r] = __shfl(al, quad * 4 + r);
#pragma unroll
    for (int cb = 0; cb < 8; ++cb)
#pragma unroll
      for (int r = 0; r < 4; ++r) accO[cb][r] *= af4[r];

    // P^T (C-layout) -> LDS [q][k] (packed b64 writes) -> A-frags
#pragma unroll
    for (int mf = 0; mf < 4; ++mf) {
      union { unsigned short s[4]; unsigned long long d; } pk;
#pragma unroll
      for (int r = 0; r < 4; ++r) pk.s[r] = f2bf(p[mf][r]);
      *(unsigned long long*)(lp + l15 * 88 + mf * 16 + quad * 4) = pk.d;
    }
    bf16x8 ap0 = *(const bf16x8*)(lp + l15 * 88 + quad * 8);
    bf16x8 ap1 = *(const bf16x8*)(lp + l15 * 88 + 32 + quad * 8);

    // PV from staged Vt slabs
#pragma unroll
    for (int cb = 0; cb < 8; ++cb) {
      bf16x8 bv0 = *(const bf16x8*)(ldsV + (cb * 16 + l15) * 32 + quad * 8);
      bf16x8 bv1 = *(const bf16x8*)(ldsV + 4096 + (cb * 16 + l15) * 32 + quad * 8);
      accO[cb] = MFMA(ap0, bv0, accO[cb]);
      accO[cb] = MFMA(ap1, bv1, accO[cb]);
    }
  }

  float lr[4];
#pragma unroll
  for (int r = 0; r < 4; ++r) lr[r] = __shfl(l_run, quad * 4 + r);
  unsigned short* ob = O + (size_t)(b * SS + q0w + quad * 4) * HH + h * HDD + l15;
#pragma unroll
  for (int cb = 0; cb < 8; ++cb)
#pragma unroll
    for (int r = 0; r < 4; ++r)
      ob[(size_t)r * HH + cb * 16] = f2bf(accO[cb][r] / lr[r]);
}

extern "C" void kernel_launch(void* const* d_in, const int* in_sizes, int n_in,
                              void* d_out, int out_size, void* d_ws, size_t ws_size,
                              hipStream_t stream) {
  const float* x = (const float*)d_in[0];
  const int* wq = (const int*)d_in[2];
  const float* wqs = (const float*)d_in[3];
  const float* bq = (const float*)d_in[4];
  const int* wk = (const int*)d_in[5];
  const float* wks = (const float*)d_in[6];
  const float* bk = (const float*)d_in[7];
  const int* wv = (const int*)d_in[8];
  const float* wvs = (const float*)d_in[9];
  const int* wo = (const int*)d_in[10];
  const float* wos = (const float*)d_in[11];
  float* out = (float*)d_out;
  char* ws = (char*)d_ws;

  // workspace (MiB offsets), lifetime-packed, peak 112 MiB:
  unsigned short* x_bf    = (unsigned short*)(ws + (0ull  << 20)); // 16  [cvt, qkv-gemm]
  unsigned short* wqkv_bf = (unsigned short*)(ws + (16ull << 20)); // 48  [cvt, qkv-gemm]
  unsigned short* Pq0     = (unsigned short*)(ws + (64ull << 20)); // 24  fp16 [gemm, epis]
  unsigned short* Pq1     = (unsigned short*)(ws + (88ull << 20)); // 24  fp16
  unsigned short* q_bf    = (unsigned short*)(ws + (0ull  << 20)); // 16  [epi, attn] (over x_bf)
  unsigned short* k_bf    = (unsigned short*)(ws + (16ull << 20)); // 4   [epi, attn] (over wqkv head)
  unsigned short* v_t     = (unsigned short*)(ws + (20ull << 20)); // 4   [epi, attn]
  unsigned short* wo_bf   = (unsigned short*)(ws + (24ull << 20)); // 32  [cvt(after qkv-gemm), o-gemm]
  unsigned short* a_bf    = (unsigned short*)(ws + (64ull << 20)); // 16  [attn, o-gemm] (over Pq0)
  unsigned short* Po0     = (unsigned short*)(ws + (80ull << 20)); // 16  fp16 [o-gemm, epi_o]
  unsigned short* Po1     = (unsigned short*)(ws + (96ull << 20)); // 16  fp16
  if (ws_size < (112ull << 20)) return;

  cvt_f32_bf16<<<8192, 256, 0, stream>>>(x, x_bf, MR * HH / 4);
  cvt_i32_bf16<<<16384, 256, 0, stream>>>(wq, wqkv_bf, HH * HH / 4);
  cvt_i32_bf16<<<4096, 256, 0, stream>>>(wk, wqkv_bf + (size_t)HH * HH, KVD * HH / 4);
  cvt_i32_bf16<<<4096, 256, 0, stream>>>(wv, wqkv_bf + (size_t)(HH + KVD) * HH, KVD * HH / 4);

  gemm_splitk<<<dim3(NQKVD / 128, MR / 128, 2), 256, 0, stream>>>(x_bf, wqkv_bf, Pq0, NQKVD);

  cvt_i32_bf16<<<16384, 256, 0, stream>>>(wo, wo_bf, HH * HH / 4);  // wqkv_bf dead now

  epi_qk<<<dim3(5, MR), 256, 0, stream>>>(Pq0, Pq1, wqs, bq, wks, bk, q_bf, k_bf);
  epi_v<<<dim3(16, 32), 256, 0, stream>>>(Pq0, Pq1, wvs, v_t);

  attn_kernel<<<dim3(16, NHH, BB), 256, 0, stream>>>(q_bf, k_bf, v_t, a_bf);

  gemm_splitk<<<dim3(HH / 128, MR / 128, 2), 256, 0, stream>>>(a_bf, wo_bf, Po0, HH);
  epi_o<<<dim3(4, MR), 256, 0, stream>>>(Po0, Po1, wos, out);
}

// Round 5
// 454.590 us; speedup vs baseline: 1.8144x; 1.1650x over previous
//
#include <hip/hip_runtime.h>
#include <math.h>

// Problem constants
#define BB   2
#define SS   1024
#define HH   4096
#define NHH  32
#define NKVV 8
#define HDD  128
#define MR   2048   // B*S
#define KVD  1024   // NKV*HD
#define NQKVD 6144  // H + 2*KVD
#define KD   4096
#define KHALF 2048
#define SCALE_F 0.08838834764831845f  // 1/sqrt(128)

typedef __attribute__((ext_vector_type(8))) short bf16x8;
typedef __attribute__((ext_vector_type(4))) float f32x4;
typedef __attribute__((ext_vector_type(4))) int i32x4;

#define MFMA(a, b, c) __builtin_amdgcn_mfma_f32_16x16x32_bf16((a), (b), (c), 0, 0, 0)
#define MFMA_I8(a, b, c) __builtin_amdgcn_mfma_i32_16x16x64_i8((a), (b), (c), 0, 0, 0)

__device__ __forceinline__ unsigned short f2bf(float f) {
  union { float f; unsigned u; } v; v.f = f;
  return (unsigned short)((v.u + 0x7fffu + ((v.u >> 16) & 1u)) >> 16);
}
__device__ __forceinline__ unsigned short f2h(float f) {
  union { _Float16 h; unsigned short s; } v; v.h = (_Float16)f; return v.s;
}
__device__ __forceinline__ float h2f(unsigned short s) {
  union { unsigned short s; _Float16 h; } v; v.s = s; return (float)v.h;
}
__device__ __forceinline__ float bf2f(unsigned short s) {
  union { unsigned u; float f; } v; v.u = ((unsigned)s) << 16; return v.f;
}
__device__ __forceinline__ float4 ld4h(const unsigned short* p) {
  uint2 d = *(const uint2*)p;
  float4 r;
  r.x = h2f((unsigned short)(d.x & 0xffff)); r.y = h2f((unsigned short)(d.x >> 16));
  r.z = h2f((unsigned short)(d.y & 0xffff)); r.w = h2f((unsigned short)(d.y >> 16));
  return r;
}

__device__ __forceinline__ void gload_lds16(const void* g, void* l) {
  __builtin_amdgcn_global_load_lds(
      (const __attribute__((address_space(1))) void*)g,
      (__attribute__((address_space(3))) void*)l, 16, 0, 0);
}

__device__ __forceinline__ signed char q8(float x, float inv) {
  float r = rintf(x * inv);
  r = fmaxf(-127.f, fminf(127.f, r));
  return (signed char)(int)r;
}

// ---------------- weight conversion: int32 -> int8, 16 elems/thread ----------------
__global__ void cvt_w_i8(const int* __restrict__ in, signed char* __restrict__ out, int n16) {
  int i = blockIdx.x * 256 + threadIdx.x;
  if (i >= n16) return;
  const int4* p = (const int4*)in + (size_t)i * 4;
  union { signed char c[16]; int4 q; } o;
#pragma unroll
  for (int j = 0; j < 4; ++j) {
    int4 v = p[j];
    o.c[j * 4 + 0] = (signed char)v.x; o.c[j * 4 + 1] = (signed char)v.y;
    o.c[j * 4 + 2] = (signed char)v.z; o.c[j * 4 + 3] = (signed char)v.w;
  }
  ((int4*)out)[i] = o.q;
}

// ---------------- per-row quantization: one 256-thread block per row of 4096 ----------------
__global__ void quant_f32(const float* __restrict__ in, signed char* __restrict__ out,
                          float* __restrict__ scale) {
  __shared__ float wm[4];
  const int row = blockIdx.x;
  const int t = threadIdx.x;
  const float4* p = (const float4*)(in + (size_t)row * HH) + t * 4;
  float4 v[4];
  float m = 0.f;
#pragma unroll
  for (int j = 0; j < 4; ++j) {
    v[j] = p[j];
    m = fmaxf(m, fmaxf(fmaxf(fabsf(v[j].x), fabsf(v[j].y)), fmaxf(fabsf(v[j].z), fabsf(v[j].w))));
  }
#pragma unroll
  for (int o = 32; o; o >>= 1) m = fmaxf(m, __shfl_xor(m, o));
  if ((t & 63) == 0) wm[t >> 6] = m;
  __syncthreads();
  m = fmaxf(fmaxf(wm[0], wm[1]), fmaxf(wm[2], wm[3]));
  m = fmaxf(m, 1e-12f);
  const float inv = 127.f / m;
  union { signed char c[16]; int4 q; } o;
#pragma unroll
  for (int j = 0; j < 4; ++j) {
    o.c[j * 4 + 0] = q8(v[j].x, inv); o.c[j * 4 + 1] = q8(v[j].y, inv);
    o.c[j * 4 + 2] = q8(v[j].z, inv); o.c[j * 4 + 3] = q8(v[j].w, inv);
  }
  ((int4*)(out + (size_t)row * HH))[t] = o.q;
  if (t == 0) scale[row] = m / 127.f;
}

__global__ void quant_bf16(const unsigned short* __restrict__ in, signed char* __restrict__ out,
                           float* __restrict__ scale) {
  __shared__ float wm[4];
  const int row = blockIdx.x;
  const int t = threadIdx.x;
  const uint4* p = (const uint4*)(in + (size_t)row * HH) + t * 2;
  float f[16];
  float m = 0.f;
#pragma unroll
  for (int j = 0; j < 2; ++j) {
    uint4 d = p[j];
    unsigned u[4] = {d.x, d.y, d.z, d.w};
#pragma unroll
    for (int k = 0; k < 4; ++k) {
      f[j * 8 + k * 2] = bf2f((unsigned short)(u[k] & 0xffff));
      f[j * 8 + k * 2 + 1] = bf2f((unsigned short)(u[k] >> 16));
    }
  }
#pragma unroll
  for (int e = 0; e < 16; ++e) m = fmaxf(m, fabsf(f[e]));
#pragma unroll
  for (int o = 32; o; o >>= 1) m = fmaxf(m, __shfl_xor(m, o));
  if ((t & 63) == 0) wm[t >> 6] = m;
  __syncthreads();
  m = fmaxf(fmaxf(wm[0], wm[1]), fmaxf(wm[2], wm[3]));
  m = fmaxf(m, 1e-12f);
  const float inv = 127.f / m;
  union { signed char c[16]; int4 q; } o;
#pragma unroll
  for (int e = 0; e < 16; ++e) o.c[e] = q8(f[e], inv);
  ((int4*)(out + (size_t)row * HH))[t] = o.q;
  if (t == 0) scale[row] = m / 127.f;
}

// ---------------- split-K i8 GEMM: P[kz] = (A_i8 * W_i8^T) * sRow * sCol -> fp16 ----------------
// 128x128 tile, BK=64 (byte-identical staging to the bf16 BK=32 version; half the k-steps).
// MODE 0: QKV (col scale from 3 concatenated regions). MODE 1: O-proj (single scale).
template <int MODE>
__global__ __launch_bounds__(256) void gemm_i8(
    const signed char* __restrict__ A, const signed char* __restrict__ W,
    const float* __restrict__ sRow,
    const float* __restrict__ s0, const float* __restrict__ s1, const float* __restrict__ s2,
    unsigned short* __restrict__ P, int N) {
  __shared__ signed char ldsA[128 * 64];
  __shared__ signed char ldsB[128 * 64];
  const int t = threadIdx.x;
  const int lane = t & 63;
  const int w = t >> 6;
  const int wr = w & 1, wc = w >> 1;
  const int l15 = lane & 15, quad = lane >> 4;
  const int bm = blockIdx.y, bn = blockIdx.x, kz = blockIdx.z;

  const int srow_ = t >> 2;
  const int scol_ = (t & 3) * 16;
  const signed char* gA = A + (size_t)(bm * 128 + srow_) * KD + scol_ + kz * KHALF;
  const signed char* gW = W + (size_t)(bn * 128 + srow_) * KD + scol_ + kz * KHALF;
  signed char* lA = ldsA + t * 16;  // wave base + lane*16 (global_load_lds layout rule)
  signed char* lB = ldsB + t * 16;

  i32x4 acc[4][4] = {};

  for (int k0 = 0; k0 < KHALF; k0 += 64) {
    __syncthreads();
    gload_lds16(gA + k0, lA);
    gload_lds16(gA + (size_t)64 * KD + k0, lA + 4096);
    gload_lds16(gW + k0, lB);
    gload_lds16(gW + (size_t)64 * KD + k0, lB + 4096);
    __syncthreads();
    i32x4 af[4], bfr[4];
#pragma unroll
    for (int mi = 0; mi < 4; ++mi)
      af[mi] = *(const i32x4*)(ldsA + (wr * 64 + mi * 16 + l15) * 64 + quad * 16);
#pragma unroll
    for (int ni = 0; ni < 4; ++ni)
      bfr[ni] = *(const i32x4*)(ldsB + (wc * 64 + ni * 16 + l15) * 64 + quad * 16);
#pragma unroll
    for (int mi = 0; mi < 4; ++mi)
#pragma unroll
      for (int ni = 0; ni < 4; ++ni)
        acc[mi][ni] = MFMA_I8(af[mi], bfr[ni], acc[mi][ni]);
  }

  // C/D layout: row = quad*4 + r, col = lane&15 (dtype-independent, m121-128)
  unsigned short* Pz = P + (size_t)kz * MR * N;
  const int row0 = bm * 128 + wr * 64 + quad * 4;
  const int col0 = bn * 128 + wc * 64 + l15;
#pragma unroll
  for (int ni = 0; ni < 4; ++ni) {
    const int col = col0 + ni * 16;
    float sc;
    if (MODE == 0)
      sc = (col < HH) ? s0[col] : (col < HH + KVD) ? s1[col - HH] : s2[col - HH - KVD];
    else
      sc = s0[col];
#pragma unroll
    for (int mi = 0; mi < 4; ++mi)
#pragma unroll
      for (int r = 0; r < 4; ++r) {
        const int row = row0 + mi * 16 + r;
        const float v = (float)acc[mi][ni][r] * sRow[row] * sc;
        Pz[(size_t)row * N + col] = f2h(v);
      }
  }
}

// ---------------- epilogues (sum 2 fp16 partial halves; scales already applied) ----------------
__global__ void epi_qk(const unsigned short* __restrict__ P0, const unsigned short* __restrict__ P1,
                       const float* __restrict__ bQ, const float* __restrict__ bK,
                       unsigned short* __restrict__ oQ, unsigned short* __restrict__ oK) {
  const int col = (blockIdx.x * 256 + threadIdx.x) * 4;
  const int row = blockIdx.y;
  const size_t off = (size_t)row * NQKVD + col;
  float4 a = ld4h(P0 + off), b2 = ld4h(P1 + off);
  union { unsigned short s[4]; uint2 d; } o;
  if (col < HH) {
    const float4 b = *(const float4*)(bQ + col);
    o.s[0] = f2bf(a.x + b2.x + b.x); o.s[1] = f2bf(a.y + b2.y + b.y);
    o.s[2] = f2bf(a.z + b2.z + b.z); o.s[3] = f2bf(a.w + b2.w + b.w);
    *(uint2*)(oQ + (size_t)row * HH + col) = o.d;
  } else {
    const int c = col - HH;
    const float4 b = *(const float4*)(bK + c);
    o.s[0] = f2bf(a.x + b2.x + b.x); o.s[1] = f2bf(a.y + b2.y + b.y);
    o.s[2] = f2bf(a.z + b2.z + b.z); o.s[3] = f2bf(a.w + b2.w + b.w);
    *(uint2*)(oK + (size_t)row * KVD + c) = o.d;
  }
}

__global__ void epi_v(const unsigned short* __restrict__ P0, const unsigned short* __restrict__ P1,
                      unsigned short* __restrict__ oVt) {
  __shared__ unsigned short lds_t[64][65];
  const int t = threadIdx.x;
  const int c0 = blockIdx.x * 64;
  const int r0 = blockIdx.y * 64;
  const int c4 = (t & 15) * 4;
#pragma unroll
  for (int rr = 0; rr < 4; ++rr) {
    const int rl = (t >> 4) * 4 + rr;
    const size_t off = (size_t)(r0 + rl) * NQKVD + (HH + KVD) + c0 + c4;
    float4 a = ld4h(P0 + off), b = ld4h(P1 + off);
    lds_t[c4 + 0][rl] = f2bf(a.x + b.x);
    lds_t[c4 + 1][rl] = f2bf(a.y + b.y);
    lds_t[c4 + 2][rl] = f2bf(a.z + b.z);
    lds_t[c4 + 3][rl] = f2bf(a.w + b.w);
  }
  __syncthreads();
  const int cl = t >> 2;
  const int rs = (t & 3) * 16;
  union { unsigned short s[16]; uint4 q[2]; } o;
#pragma unroll
  for (int i = 0; i < 16; ++i) o.s[i] = lds_t[cl][rs + i];
  uint4* dst = (uint4*)(oVt + (size_t)(c0 + cl) * MR + r0 + rs);
  dst[0] = o.q[0]; dst[1] = o.q[1];
}

__global__ void epi_o(const unsigned short* __restrict__ P0, const unsigned short* __restrict__ P1,
                      float* __restrict__ out) {
  const int col = (blockIdx.x * 256 + threadIdx.x) * 4;
  const int row = blockIdx.y;
  const size_t off = (size_t)row * HH + col;
  float4 a = ld4h(P0 + off), b = ld4h(P1 + off);
  *(float4*)(out + off) = make_float4(a.x + b.x, a.y + b.y, a.z + b.z, a.w + b.w);
}

// ---------------- flash attention: 4-wave blocks, 64-row Q tile, LDS-staged K/V ----------------
__global__ __launch_bounds__(256, 3) void attn_kernel(
    const unsigned short* __restrict__ Q,   // [2048][4096]
    const unsigned short* __restrict__ K,   // [2048][1024]
    const unsigned short* __restrict__ Vt,  // [1024][2048]
    unsigned short* __restrict__ O) {       // [2048][4096]
  __shared__ unsigned short ldsK[4 * 64 * 32];   // [kk][krow][32]  16 KB
  __shared__ unsigned short ldsV[2 * 128 * 32];  // [kc][hd][32]    16 KB
  __shared__ unsigned short ldsP[4][16 * 88];    // per-wave P tile 11 KB
  const int t = threadIdx.x;
  const int lane = t & 63;
  const int wv = t >> 6;
  const int l15 = lane & 15, quad = lane >> 4;
  const int qt = 15 - blockIdx.x;  // heavy-first
  const int h = blockIdx.y;
  const int b = blockIdx.z;
  const int kv = h >> 2;
  const int q0w = qt * 64 + wv * 16;
  const int q = q0w + l15;

  bf16x8 bq[4];
  const unsigned short* qbase = Q + (size_t)(b * SS + q0w + l15) * HH + h * HDD + quad * 8;
#pragma unroll
  for (int kk = 0; kk < 4; ++kk) bq[kk] = *(const bf16x8*)(qbase + kk * 32);

  const unsigned short* gK = K + (size_t)(b * SS) * KVD + kv * HDD + wv * 32 + (lane & 3) * 8;
  const unsigned short* gV = Vt + (size_t)(kv * HDD + wv * 32 + (lane >> 2)) * MR + b * SS + (lane & 3) * 8;
  unsigned short* lK = ldsK + wv * 2048 + lane * 8;
  unsigned short* lV = ldsV + (size_t)wv * 32 * 32 + lane * 8;
  unsigned short* lp = ldsP[wv];

  f32x4 accO[8] = {};
  float m_run = -1e30f, l_run = 0.f;

  for (int kt = 0; kt <= qt; ++kt) {
    const int k0 = kt * 64;
    __syncthreads();
#pragma unroll
    for (int j = 0; j < 4; ++j)
      gload_lds16(gK + (size_t)(k0 + j * 16 + (lane >> 2)) * KVD, lK + j * 512);
#pragma unroll
    for (int kc = 0; kc < 2; ++kc)
#pragma unroll
      for (int j = 0; j < 2; ++j)
        gload_lds16(gV + (size_t)j * 16 * MR + k0 + kc * 32,
                    lV + kc * 4096 + j * 512);
    __syncthreads();

    f32x4 st[4] = {};
#pragma unroll
    for (int kk = 0; kk < 4; ++kk)
#pragma unroll
      for (int mf = 0; mf < 4; ++mf) {
        bf16x8 af = *(const bf16x8*)(ldsK + kk * 2048 + (mf * 16 + l15) * 32 + quad * 8);
        st[mf] = MFMA(af, bq[kk], st[mf]);
      }

    float p[4][4];
    float cm = -1e30f;
#pragma unroll
    for (int mf = 0; mf < 4; ++mf)
#pragma unroll
      for (int r = 0; r < 4; ++r) {
        const int k = k0 + mf * 16 + quad * 4 + r;
        float v = st[mf][r] * SCALE_F;
        if (k > q) v = -1e30f;
        p[mf][r] = v;
        cm = fmaxf(cm, v);
      }
    cm = fmaxf(cm, __shfl_xor(cm, 16));
    cm = fmaxf(cm, __shfl_xor(cm, 32));
    const float mn = fmaxf(m_run, cm);
    const float al = __expf(m_run - mn);
    float sum = 0.f;
#pragma unroll
    for (int mf = 0; mf < 4; ++mf)
#pragma unroll
      for (int r = 0; r < 4; ++r) {
        const float e = __expf(p[mf][r] - mn);
        p[mf][r] = e;
        sum += e;
      }
    sum += __shfl_xor(sum, 16);
    sum += __shfl_xor(sum, 32);
    l_run = l_run * al + sum;
    m_run = mn;
    float af4[4];
#pragma unroll
    for (int r = 0; r < 4; ++r) af4[r] = __shfl(al, quad * 4 + r);
#pragma unroll
    for (int cb = 0; cb < 8; ++cb)
#pragma unroll
      for (int r = 0; r < 4; ++r) accO[cb][r] *= af4[r];

#pragma unroll
    for (int mf = 0; mf < 4; ++mf) {
      union { unsigned short s[4]; unsigned long long d; } pk;
#pragma unroll
      for (int r = 0; r < 4; ++r) pk.s[r] = f2bf(p[mf][r]);
      *(unsigned long long*)(lp + l15 * 88 + mf * 16 + quad * 4) = pk.d;
    }
    bf16x8 ap0 = *(const bf16x8*)(lp + l15 * 88 + quad * 8);
    bf16x8 ap1 = *(const bf16x8*)(lp + l15 * 88 + 32 + quad * 8);

#pragma unroll
    for (int cb = 0; cb < 8; ++cb) {
      bf16x8 bv0 = *(const bf16x8*)(ldsV + (cb * 16 + l15) * 32 + quad * 8);
      bf16x8 bv1 = *(const bf16x8*)(ldsV + 4096 + (cb * 16 + l15) * 32 + quad * 8);
      accO[cb] = MFMA(ap0, bv0, accO[cb]);
      accO[cb] = MFMA(ap1, bv1, accO[cb]);
    }
  }

  float lr[4];
#pragma unroll
  for (int r = 0; r < 4; ++r) lr[r] = __shfl(l_run, quad * 4 + r);
  unsigned short* ob = O + (size_t)(b * SS + q0w + quad * 4) * HH + h * HDD + l15;
#pragma unroll
  for (int cb = 0; cb < 8; ++cb)
#pragma unroll
    for (int r = 0; r < 4; ++r)
      ob[(size_t)r * HH + cb * 16] = f2bf(accO[cb][r] / lr[r]);
}

extern "C" void kernel_launch(void* const* d_in, const int* in_sizes, int n_in,
                              void* d_out, int out_size, void* d_ws, size_t ws_size,
                              hipStream_t stream) {
  const float* x = (const float*)d_in[0];
  const int* wq = (const int*)d_in[2];
  const float* wqs = (const float*)d_in[3];
  const float* bq = (const float*)d_in[4];
  const int* wk = (const int*)d_in[5];
  const float* wks = (const float*)d_in[6];
  const float* bk = (const float*)d_in[7];
  const int* wv = (const int*)d_in[8];
  const float* wvs = (const float*)d_in[9];
  const int* wo = (const int*)d_in[10];
  const float* wos = (const float*)d_in[11];
  float* out = (float*)d_out;
  char* ws = (char*)d_ws;

  // workspace (MiB offsets), lifetime-packed, guard 130 MiB (ws >= 136 proven round 1):
  signed char*    x_i8    = (signed char*)   (ws + (0ull   << 20)); // 8   [quant, qkv-gemm]
  signed char*    wqkv_i8 = (signed char*)   (ws + (8ull   << 20)); // 24  [cvt, qkv-gemm]
  signed char*    wo_i8   = (signed char*)   (ws + (32ull  << 20)); // 16  [cvt, o-gemm]
  unsigned short* Pq      = (unsigned short*)(ws + (48ull  << 20)); // 48  fp16 x2 [gemm, epis]
  unsigned short* q_bf    = (unsigned short*)(ws + (0ull   << 20)); // 16  [epi, attn] (over x_i8+wqkv head)
  unsigned short* k_bf    = (unsigned short*)(ws + (16ull  << 20)); // 4   [epi, attn] (over wqkv)
  unsigned short* v_t     = (unsigned short*)(ws + (20ull  << 20)); // 4   [epi, attn] (over wqkv)
  unsigned short* a_bf    = (unsigned short*)(ws + (48ull  << 20)); // 16  [attn, quant_a] (over Pq0)
  signed char*    a_i8    = (signed char*)   (ws + (64ull  << 20)); // 8   [quant_a, o-gemm] (over Pq)
  unsigned short* Po      = (unsigned short*)(ws + (96ull  << 20)); // 32  fp16 x2 [o-gemm, epi_o]
  float*          sx      = (float*)         (ws + (128ull << 20)); // 8 KB
  float*          sa      = (float*)         (ws + (129ull << 20)); // 8 KB
  if (ws_size < (130ull << 20)) return;

  quant_f32<<<MR, 256, 0, stream>>>(x, x_i8, sx);
  cvt_w_i8<<<4096, 256, 0, stream>>>(wq, wqkv_i8, HH * HH / 16);
  cvt_w_i8<<<1024, 256, 0, stream>>>(wk, wqkv_i8 + (size_t)HH * HH, KVD * HH / 16);
  cvt_w_i8<<<1024, 256, 0, stream>>>(wv, wqkv_i8 + (size_t)(HH + KVD) * HH, KVD * HH / 16);
  cvt_w_i8<<<4096, 256, 0, stream>>>(wo, wo_i8, HH * HH / 16);

  gemm_i8<0><<<dim3(NQKVD / 128, MR / 128, 2), 256, 0, stream>>>(
      x_i8, wqkv_i8, sx, wqs, wks, wvs, Pq, NQKVD);

  epi_qk<<<dim3(5, MR), 256, 0, stream>>>(Pq, Pq + (size_t)MR * NQKVD, bq, bk, q_bf, k_bf);
  epi_v<<<dim3(16, 32), 256, 0, stream>>>(Pq, Pq + (size_t)MR * NQKVD, v_t);

  attn_kernel<<<dim3(16, NHH, BB), 256, 0, stream>>>(q_bf, k_bf, v_t, a_bf);

  quant_bf16<<<MR, 256, 0, stream>>>(a_bf, a_i8, sa);
  gemm_i8<1><<<dim3(HH / 128, MR / 128, 2), 256, 0, stream>>>(
      a_i8, wo_i8, sa, wos, nullptr, nullptr, Po, HH);
  epi_o<<<dim3(4, MR), 256, 0, stream>>>(Po, Po + (size_t)MR * HH, out);
}

// Round 6
// 426.469 us; speedup vs baseline: 1.9340x; 1.0659x over previous
//
#include <hip/hip_runtime.h>
#include <math.h>

// Problem constants
#define BB   2
#define SS   1024
#define HH   4096
#define NHH  32
#define NKVV 8
#define HDD  128
#define MR   2048   // B*S
#define KVD  1024   // NKV*HD
#define NQKVD 6144  // H + 2*KVD
#define KD   4096
#define KHALF 2048
#define SCALE_F 0.08838834764831845f  // 1/sqrt(128)

typedef __attribute__((ext_vector_type(8))) short bf16x8;
typedef __attribute__((ext_vector_type(4))) float f32x4;
typedef __attribute__((ext_vector_type(4))) int i32x4;

#define MFMA(a, b, c) __builtin_amdgcn_mfma_f32_16x16x32_bf16((a), (b), (c), 0, 0, 0)
#define MFMA_I8(a, b, c) __builtin_amdgcn_mfma_i32_16x16x64_i8((a), (b), (c), 0, 0, 0)

__device__ __forceinline__ unsigned short f2bf(float f) {
  union { float f; unsigned u; } v; v.f = f;
  return (unsigned short)((v.u + 0x7fffu + ((v.u >> 16) & 1u)) >> 16);
}
__device__ __forceinline__ unsigned short f2h(float f) {
  union { _Float16 h; unsigned short s; } v; v.h = (_Float16)f; return v.s;
}
__device__ __forceinline__ float h2f(unsigned short s) {
  union { unsigned short s; _Float16 h; } v; v.s = s; return (float)v.h;
}
__device__ __forceinline__ float bf2f(unsigned short s) {
  union { unsigned u; float f; } v; v.u = ((unsigned)s) << 16; return v.f;
}
__device__ __forceinline__ float4 ld4h(const unsigned short* p) {
  uint2 d = *(const uint2*)p;
  float4 r;
  r.x = h2f((unsigned short)(d.x & 0xffff)); r.y = h2f((unsigned short)(d.x >> 16));
  r.z = h2f((unsigned short)(d.y & 0xffff)); r.w = h2f((unsigned short)(d.y >> 16));
  return r;
}

__device__ __forceinline__ void gload_lds16(const void* g, void* l) {
  __builtin_amdgcn_global_load_lds(
      (const __attribute__((address_space(1))) void*)g,
      (__attribute__((address_space(3))) void*)l, 16, 0, 0);
}

__device__ __forceinline__ signed char q8(float x, float inv) {
  float r = rintf(x * inv);
  r = fmaxf(-127.f, fminf(127.f, r));
  return (signed char)(int)r;
}

// ---------------- fused weight conversion: all 4 matrices, int32 -> int8 ----------------
#define NQ16 ((size_t)HH * HH / 16)
#define NK16 ((size_t)KVD * HH / 16)
__global__ void cvt_w_all(const int* __restrict__ wq, const int* __restrict__ wk,
                          const int* __restrict__ wv, const int* __restrict__ wo,
                          signed char* __restrict__ wqkv, signed char* __restrict__ wo8) {
  size_t i = (size_t)blockIdx.x * 256 + threadIdx.x;  // 16-elem chunk id
  const int* src;
  signed char* dst;
  if (i < NQ16) { src = wq; dst = wqkv; }
  else if (i < NQ16 + NK16) { src = wk - NQ16 * 16; dst = wqkv; }
  else if (i < NQ16 + 2 * NK16) { src = wv - (NQ16 + NK16) * 16; dst = wqkv; }
  else { src = wo - (NQ16 + 2 * NK16) * 16; dst = wo8 - (NQ16 + 2 * NK16) * 16; }
  const int4* p = (const int4*)(src + i * 16);
  union { signed char c[16]; int4 q; } o;
#pragma unroll
  for (int j = 0; j < 4; ++j) {
    int4 v = p[j];
    o.c[j * 4 + 0] = (signed char)v.x; o.c[j * 4 + 1] = (signed char)v.y;
    o.c[j * 4 + 2] = (signed char)v.z; o.c[j * 4 + 3] = (signed char)v.w;
  }
  *(int4*)(dst + i * 16) = o.q;
}

// ---------------- per-row quantization: one 256-thread block per row of 4096 ----------------
__global__ void quant_f32(const float* __restrict__ in, signed char* __restrict__ out,
                          float* __restrict__ scale) {
  __shared__ float wm[4];
  const int row = blockIdx.x;
  const int t = threadIdx.x;
  const float4* p = (const float4*)(in + (size_t)row * HH) + t * 4;
  float4 v[4];
  float m = 0.f;
#pragma unroll
  for (int j = 0; j < 4; ++j) {
    v[j] = p[j];
    m = fmaxf(m, fmaxf(fmaxf(fabsf(v[j].x), fabsf(v[j].y)), fmaxf(fabsf(v[j].z), fabsf(v[j].w))));
  }
#pragma unroll
  for (int o = 32; o; o >>= 1) m = fmaxf(m, __shfl_xor(m, o));
  if ((t & 63) == 0) wm[t >> 6] = m;
  __syncthreads();
  m = fmaxf(fmaxf(wm[0], wm[1]), fmaxf(wm[2], wm[3]));
  m = fmaxf(m, 1e-12f);
  const float inv = 127.f / m;
  union { signed char c[16]; int4 q; } o;
#pragma unroll
  for (int j = 0; j < 4; ++j) {
    o.c[j * 4 + 0] = q8(v[j].x, inv); o.c[j * 4 + 1] = q8(v[j].y, inv);
    o.c[j * 4 + 2] = q8(v[j].z, inv); o.c[j * 4 + 3] = q8(v[j].w, inv);
  }
  ((int4*)(out + (size_t)row * HH))[t] = o.q;
  if (t == 0) scale[row] = m / 127.f;
}

__global__ void quant_bf16(const unsigned short* __restrict__ in, signed char* __restrict__ out,
                           float* __restrict__ scale) {
  __shared__ float wm[4];
  const int row = blockIdx.x;
  const int t = threadIdx.x;
  const uint4* p = (const uint4*)(in + (size_t)row * HH) + t * 2;
  float f[16];
  float m = 0.f;
#pragma unroll
  for (int j = 0; j < 2; ++j) {
    uint4 d = p[j];
    unsigned u[4] = {d.x, d.y, d.z, d.w};
#pragma unroll
    for (int k = 0; k < 4; ++k) {
      f[j * 8 + k * 2] = bf2f((unsigned short)(u[k] & 0xffff));
      f[j * 8 + k * 2 + 1] = bf2f((unsigned short)(u[k] >> 16));
    }
  }
#pragma unroll
  for (int e = 0; e < 16; ++e) m = fmaxf(m, fabsf(f[e]));
#pragma unroll
  for (int o = 32; o; o >>= 1) m = fmaxf(m, __shfl_xor(m, o));
  if ((t & 63) == 0) wm[t >> 6] = m;
  __syncthreads();
  m = fmaxf(fmaxf(wm[0], wm[1]), fmaxf(wm[2], wm[3]));
  m = fmaxf(m, 1e-12f);
  const float inv = 127.f / m;
  union { signed char c[16]; int4 q; } o;
#pragma unroll
  for (int e = 0; e < 16; ++e) o.c[e] = q8(f[e], inv);
  ((int4*)(out + (size_t)row * HH))[t] = o.q;
  if (t == 0) scale[row] = m / 127.f;
}

// ---------------- split-K i8 GEMM, BK=128, XOR-swizzled staging ----------------
// 128x128 tile. 32 MFMA per barrier (2x round-5's 16). Row stride 128B = 32 banks,
// so staging XOR-swizzles the global source column (chunk ^= row&7); reads de-swizzle
// -> conflict-free ds_read_b128. LDS dest stays contiguous (global_load_lds rule).
// MODE 0: QKV (col scale from 3 concatenated regions). MODE 1: O-proj (single scale).
template <int MODE>
__global__ __launch_bounds__(256) void gemm_i8(
    const signed char* __restrict__ A, const signed char* __restrict__ W,
    const float* __restrict__ sRow,
    const float* __restrict__ s0, const float* __restrict__ s1, const float* __restrict__ s2,
    unsigned short* __restrict__ P, int N) {
  __shared__ signed char ldsA[128 * 128];
  __shared__ signed char ldsB[128 * 128];
  const int t = threadIdx.x;
  const int lane = t & 63;
  const int w = t >> 6;
  const int wr = w & 1, wc = w >> 1;
  const int l15 = lane & 15, quad = lane >> 4;
  const int bm = blockIdx.y, bn = blockIdx.x, kz = blockIdx.z;

  const int srow_ = t >> 3;                          // 0..31
  const int scol_ = ((t & 7) ^ (srow_ & 7)) * 16;    // XOR-swizzled source column
  const signed char* gA = A + (size_t)(bm * 128 + srow_) * KD + scol_ + kz * KHALF;
  const signed char* gW = W + (size_t)(bn * 128 + srow_) * KD + scol_ + kz * KHALF;
  signed char* lA = ldsA + t * 16;  // wave base + lane*16 (global_load_lds layout rule)
  signed char* lB = ldsB + t * 16;

  i32x4 acc[4][4] = {};

  for (int k0 = 0; k0 < KHALF; k0 += 128) {
    __syncthreads();
#pragma unroll
    for (int j = 0; j < 4; ++j) {
      gload_lds16(gA + (size_t)j * 32 * KD + k0, lA + j * 4096);
      gload_lds16(gW + (size_t)j * 32 * KD + k0, lB + j * 4096);
    }
    __syncthreads();
#pragma unroll
    for (int kc = 0; kc < 2; ++kc) {
      i32x4 af[4], bfr[4];
#pragma unroll
      for (int mi = 0; mi < 4; ++mi) {
        const int row = wr * 64 + mi * 16 + l15;
        const int ch = (kc * 4 + quad) ^ (row & 7);
        af[mi] = *(const i32x4*)(ldsA + row * 128 + ch * 16);
      }
#pragma unroll
      for (int ni = 0; ni < 4; ++ni) {
        const int row = wc * 64 + ni * 16 + l15;
        const int ch = (kc * 4 + quad) ^ (row & 7);
        bfr[ni] = *(const i32x4*)(ldsB + row * 128 + ch * 16);
      }
#pragma unroll
      for (int mi = 0; mi < 4; ++mi)
#pragma unroll
        for (int ni = 0; ni < 4; ++ni)
          acc[mi][ni] = MFMA_I8(af[mi], bfr[ni], acc[mi][ni]);
    }
  }

  // C/D layout: row = quad*4 + r, col = lane&15 (dtype-independent, m121-128)
  unsigned short* Pz = P + (size_t)kz * MR * N;
  const int row0 = bm * 128 + wr * 64 + quad * 4;
  const int col0 = bn * 128 + wc * 64 + l15;
#pragma unroll
  for (int ni = 0; ni < 4; ++ni) {
    const int col = col0 + ni * 16;
    float sc;
    if (MODE == 0)
      sc = (col < HH) ? s0[col] : (col < HH + KVD) ? s1[col - HH] : s2[col - HH - KVD];
    else
      sc = s0[col];
#pragma unroll
    for (int mi = 0; mi < 4; ++mi)
#pragma unroll
      for (int r = 0; r < 4; ++r) {
        const int row = row0 + mi * 16 + r;
        const float v = (float)acc[mi][ni][r] * sRow[row] * sc;
        Pz[(size_t)row * N + col] = f2h(v);
      }
  }
}

// ---------------- fused QKV epilogue: Q (bias, *1/sqrt(d)), K (bias), V (transpose) ----------------
// blocks [0,10240): Q/K cols; blocks [10240,10752): V transpose tiles.
__global__ void epi_qkv(const unsigned short* __restrict__ P0, const unsigned short* __restrict__ P1,
                        const float* __restrict__ bQ, const float* __restrict__ bK,
                        unsigned short* __restrict__ oQ, unsigned short* __restrict__ oK,
                        unsigned short* __restrict__ oVt) {
  __shared__ unsigned short lds_t[64][65];
  const int t = threadIdx.x;
  int bid = blockIdx.x;
  if (bid < 10240) {
    const int row = bid / 5;
    const int col = (bid - row * 5) * 1024 + t * 4;
    const size_t off = (size_t)row * NQKVD + col;
    float4 a = ld4h(P0 + off), b2 = ld4h(P1 + off);
    union { unsigned short s[4]; uint2 d; } o;
    if (col < HH) {
      const float4 b = *(const float4*)(bQ + col);
      o.s[0] = f2bf((a.x + b2.x + b.x) * SCALE_F);
      o.s[1] = f2bf((a.y + b2.y + b.y) * SCALE_F);
      o.s[2] = f2bf((a.z + b2.z + b.z) * SCALE_F);
      o.s[3] = f2bf((a.w + b2.w + b.w) * SCALE_F);
      *(uint2*)(oQ + (size_t)row * HH + col) = o.d;
    } else {
      const int c = col - HH;
      const float4 b = *(const float4*)(bK + c);
      o.s[0] = f2bf(a.x + b2.x + b.x); o.s[1] = f2bf(a.y + b2.y + b.y);
      o.s[2] = f2bf(a.z + b2.z + b.z); o.s[3] = f2bf(a.w + b2.w + b.w);
      *(uint2*)(oK + (size_t)row * KVD + c) = o.d;
    }
  } else {
    bid -= 10240;
    const int c0 = (bid & 15) * 64;
    const int r0 = (bid >> 4) * 64;
    const int c4 = (t & 15) * 4;
#pragma unroll
    for (int rr = 0; rr < 4; ++rr) {
      const int rl = (t >> 4) * 4 + rr;
      const size_t off = (size_t)(r0 + rl) * NQKVD + (HH + KVD) + c0 + c4;
      float4 a = ld4h(P0 + off), b = ld4h(P1 + off);
      lds_t[c4 + 0][rl] = f2bf(a.x + b.x);
      lds_t[c4 + 1][rl] = f2bf(a.y + b.y);
      lds_t[c4 + 2][rl] = f2bf(a.z + b.z);
      lds_t[c4 + 3][rl] = f2bf(a.w + b.w);
    }
    __syncthreads();
    const int cl = t >> 2;
    const int rs = (t & 3) * 16;
    union { unsigned short s[16]; uint4 q[2]; } o;
#pragma unroll
    for (int i = 0; i < 16; ++i) o.s[i] = lds_t[cl][rs + i];
    uint4* dst = (uint4*)(oVt + (size_t)(c0 + cl) * MR + r0 + rs);
    dst[0] = o.q[0]; dst[1] = o.q[1];
  }
}

__global__ void epi_o(const unsigned short* __restrict__ P0, const unsigned short* __restrict__ P1,
                      float* __restrict__ out) {
  const int col = (blockIdx.x * 256 + threadIdx.x) * 4;
  const int row = blockIdx.y;
  const size_t off = (size_t)row * HH + col;
  float4 a = ld4h(P0 + off), b = ld4h(P1 + off);
  *(float4*)(out + off) = make_float4(a.x + b.x, a.y + b.y, a.z + b.z, a.w + b.w);
}

// ---------------- flash attention: 4-wave blocks, 64-row Q tile, LDS-staged K/V ----------------
// Q pre-scaled by 1/sqrt(d) in epi_qkv.
__global__ __launch_bounds__(256, 3) void attn_kernel(
    const unsigned short* __restrict__ Q,   // [2048][4096]
    const unsigned short* __restrict__ K,   // [2048][1024]
    const unsigned short* __restrict__ Vt,  // [1024][2048]
    unsigned short* __restrict__ O) {       // [2048][4096]
  __shared__ unsigned short ldsK[4 * 64 * 32];   // [kk][krow][32]  16 KB
  __shared__ unsigned short ldsV[2 * 128 * 32];  // [kc][hd][32]    16 KB
  __shared__ unsigned short ldsP[4][16 * 88];    // per-wave P tile 11 KB
  const int t = threadIdx.x;
  const int lane = t & 63;
  const int wv = t >> 6;
  const int l15 = lane & 15, quad = lane >> 4;
  const int qt = 15 - blockIdx.x;  // heavy-first
  const int h = blockIdx.y;
  const int b = blockIdx.z;
  const int kv = h >> 2;
  const int q0w = qt * 64 + wv * 16;
  const int q = q0w + l15;

  bf16x8 bq[4];
  const unsigned short* qbase = Q + (size_t)(b * SS + q0w + l15) * HH + h * HDD + quad * 8;
#pragma unroll
  for (int kk = 0; kk < 4; ++kk) bq[kk] = *(const bf16x8*)(qbase + kk * 32);

  const unsigned short* gK = K + (size_t)(b * SS) * KVD + kv * HDD + wv * 32 + (lane & 3) * 8;
  const unsigned short* gV = Vt + (size_t)(kv * HDD + wv * 32 + (lane >> 2)) * MR + b * SS + (lane & 3) * 8;
  unsigned short* lK = ldsK + wv * 2048 + lane * 8;
  unsigned short* lV = ldsV + (size_t)wv * 32 * 32 + lane * 8;
  unsigned short* lp = ldsP[wv];

  f32x4 accO[8] = {};
  float m_run = -1e30f, l_run = 0.f;

  for (int kt = 0; kt <= qt; ++kt) {
    const int k0 = kt * 64;
    __syncthreads();
#pragma unroll
    for (int j = 0; j < 4; ++j)
      gload_lds16(gK + (size_t)(k0 + j * 16 + (lane >> 2)) * KVD, lK + j * 512);
#pragma unroll
    for (int kc = 0; kc < 2; ++kc)
#pragma unroll
      for (int j = 0; j < 2; ++j)
        gload_lds16(gV + (size_t)j * 16 * MR + k0 + kc * 32,
                    lV + kc * 4096 + j * 512);
    __syncthreads();

    f32x4 st[4] = {};
#pragma unroll
    for (int kk = 0; kk < 4; ++kk)
#pragma unroll
      for (int mf = 0; mf < 4; ++mf) {
        bf16x8 af = *(const bf16x8*)(ldsK + kk * 2048 + (mf * 16 + l15) * 32 + quad * 8);
        st[mf] = MFMA(af, bq[kk], st[mf]);
      }

    float p[4][4];
    float cm = -1e30f;
#pragma unroll
    for (int mf = 0; mf < 4; ++mf)
#pragma unroll
      for (int r = 0; r < 4; ++r) {
        const int k = k0 + mf * 16 + quad * 4 + r;
        float v = st[mf][r];
        if (k > q) v = -1e30f;
        p[mf][r] = v;
        cm = fmaxf(cm, v);
      }
    cm = fmaxf(cm, __shfl_xor(cm, 16));
    cm = fmaxf(cm, __shfl_xor(cm, 32));
    const float mn = fmaxf(m_run, cm);
    const float al = __expf(m_run - mn);
    float sum = 0.f;
#pragma unroll
    for (int mf = 0; mf < 4; ++mf)
#pragma unroll
      for (int r = 0; r < 4; ++r) {
        const float e = __expf(p[mf][r] - mn);
        p[mf][r] = e;
        sum += e;
      }
    sum += __shfl_xor(sum, 16);
    sum += __shfl_xor(sum, 32);
    l_run = l_run * al + sum;
    m_run = mn;
    float af4[4];
#pragma unroll
    for (int r = 0; r < 4; ++r) af4[r] = __shfl(al, quad * 4 + r);
#pragma unroll
    for (int cb = 0; cb < 8; ++cb)
#pragma unroll
      for (int r = 0; r < 4; ++r) accO[cb][r] *= af4[r];

#pragma unroll
    for (int mf = 0; mf < 4; ++mf) {
      union { unsigned short s[4]; unsigned long long d; } pk;
#pragma unroll
      for (int r = 0; r < 4; ++r) pk.s[r] = f2bf(p[mf][r]);
      *(unsigned long long*)(lp + l15 * 88 + mf * 16 + quad * 4) = pk.d;
    }
    bf16x8 ap0 = *(const bf16x8*)(lp + l15 * 88 + quad * 8);
    bf16x8 ap1 = *(const bf16x8*)(lp + l15 * 88 + 32 + quad * 8);

#pragma unroll
    for (int cb = 0; cb < 8; ++cb) {
      bf16x8 bv0 = *(const bf16x8*)(ldsV + (cb * 16 + l15) * 32 + quad * 8);
      bf16x8 bv1 = *(const bf16x8*)(ldsV + 4096 + (cb * 16 + l15) * 32 + quad * 8);
      accO[cb] = MFMA(ap0, bv0, accO[cb]);
      accO[cb] = MFMA(ap1, bv1, accO[cb]);
    }
  }

  float lr[4];
#pragma unroll
  for (int r = 0; r < 4; ++r) lr[r] = __shfl(l_run, quad * 4 + r);
  unsigned short* ob = O + (size_t)(b * SS + q0w + quad * 4) * HH + h * HDD + l15;
#pragma unroll
  for (int cb = 0; cb < 8; ++cb)
#pragma unroll
    for (int r = 0; r < 4; ++r)
      ob[(size_t)r * HH + cb * 16] = f2bf(accO[cb][r] / lr[r]);
}

extern "C" void kernel_launch(void* const* d_in, const int* in_sizes, int n_in,
                              void* d_out, int out_size, void* d_ws, size_t ws_size,
                              hipStream_t stream) {
  const float* x = (const float*)d_in[0];
  const int* wq = (const int*)d_in[2];
  const float* wqs = (const float*)d_in[3];
  const float* bq = (const float*)d_in[4];
  const int* wk = (const int*)d_in[5];
  const float* wks = (const float*)d_in[6];
  const float* bk = (const float*)d_in[7];
  const int* wv = (const int*)d_in[8];
  const float* wvs = (const float*)d_in[9];
  const int* wo = (const int*)d_in[10];
  const float* wos = (const float*)d_in[11];
  float* out = (float*)d_out;
  char* ws = (char*)d_ws;

  // workspace (MiB offsets), lifetime-packed, guard 130 MiB (ws >= 136 proven round 1):
  signed char*    x_i8    = (signed char*)   (ws + (0ull   << 20)); // 8   [quant, qkv-gemm]
  signed char*    wqkv_i8 = (signed char*)   (ws + (8ull   << 20)); // 24  [cvt, qkv-gemm]
  signed char*    wo_i8   = (signed char*)   (ws + (32ull  << 20)); // 16  [cvt, o-gemm]
  unsigned short* Pq      = (unsigned short*)(ws + (48ull  << 20)); // 48  fp16 x2 [gemm, epis]
  unsigned short* q_bf    = (unsigned short*)(ws + (0ull   << 20)); // 16  [epi, attn] (over x_i8+wqkv head)
  unsigned short* k_bf    = (unsigned short*)(ws + (16ull  << 20)); // 4   [epi, attn] (over wqkv)
  unsigned short* v_t     = (unsigned short*)(ws + (20ull  << 20)); // 4   [epi, attn] (over wqkv)
  unsigned short* a_bf    = (unsigned short*)(ws + (48ull  << 20)); // 16  [attn, quant_a] (over Pq0)
  signed char*    a_i8    = (signed char*)   (ws + (64ull  << 20)); // 8   [quant_a, o-gemm] (over Pq)
  unsigned short* Po      = (unsigned short*)(ws + (96ull  << 20)); // 32  fp16 x2 [o-gemm, epi_o]
  float*          sx      = (float*)         (ws + (128ull << 20)); // 8 KB
  float*          sa      = (float*)         (ws + (129ull << 20)); // 8 KB
  if (ws_size < (130ull << 20)) return;

  quant_f32<<<MR, 256, 0, stream>>>(x, x_i8, sx);
  cvt_w_all<<<10240, 256, 0, stream>>>(wq, wk, wv, wo, wqkv_i8, wo_i8);

  gemm_i8<0><<<dim3(NQKVD / 128, MR / 128, 2), 256, 0, stream>>>(
      x_i8, wqkv_i8, sx, wqs, wks, wvs, Pq, NQKVD);

  epi_qkv<<<10752, 256, 0, stream>>>(Pq, Pq + (size_t)MR * NQKVD, bq, bk, q_bf, k_bf, v_t);

  attn_kernel<<<dim3(16, NHH, BB), 256, 0, stream>>>(q_bf, k_bf, v_t, a_bf);

  quant_bf16<<<MR, 256, 0, stream>>>(a_bf, a_i8, sa);
  gemm_i8<1><<<dim3(HH / 128, MR / 128, 2), 256, 0, stream>>>(
      a_i8, wo_i8, sa, wos, nullptr, nullptr, Po, HH);
  epi_o<<<dim3(4, MR), 256, 0, stream>>>(Po, Po + (size_t)MR * HH, out);
}